// Round 13
// baseline (6637.778 us; speedup 1.0000x reference)
//
#include <hip/hip_runtime.h>
#include <hip/hip_bf16.h>
#include <cstdint>

typedef __bf16 bf16;
typedef __attribute__((ext_vector_type(8)))  __bf16 bf16x8;
typedef __attribute__((ext_vector_type(4)))  __bf16 bf16x4;
typedef __attribute__((ext_vector_type(16))) float  f32x16;
typedef __attribute__((ext_vector_type(4)))  float  f32x4;
typedef __attribute__((ext_vector_type(4)))  unsigned int u32x4;

#define KPAD 3136   // FFN K (3074) padded to 49*64
#define KS1  196    // KPAD/16

__device__ __forceinline__ f32x16 zero16() {
  f32x16 z;
#pragma unroll
  for (int i = 0; i < 16; i++) z[i] = 0.f;
  return z;
}

__device__ __forceinline__ f32x16 mfma16(bf16x8 a, bf16x8 b, f32x16 c) {
  return __builtin_amdgcn_mfma_f32_32x32x16_bf16(a, b, c, 0, 0, 0);
}

// XOR swizzle for [rows][64] bf16 LDS tiles (row stride 128B) — used by ffn1/2.
__device__ __forceinline__ unsigned swz(unsigned row, unsigned bir) {
  return row * 128u + (bir ^ ((row & 7u) << 4));
}

// ---------------------------------------------------------------------------
// prep: pack weights into fragment-direct layout  packed[((ct*KS+ks)*64+lane)*8+j]
//       = W[ks*16 + 8*(lane>>5) + j][ct*32 + (lane&31)]   (zero-padded K for W1)
//       + fold BatchNorm (+b2) into per-col scale/shift.
// ---------------------------------------------------------------------------
__global__ void prep_kernel(const float* __restrict__ Wq, const float* __restrict__ Wk,
                            const float* __restrict__ Wv, const float* __restrict__ W1,
                            const float* __restrict__ W2, const float* __restrict__ b2,
                            const float* __restrict__ gamma, const float* __restrict__ beta,
                            const float* __restrict__ mean, const float* __restrict__ var,
                            bf16* __restrict__ Wqp, bf16* __restrict__ Wkp, bf16* __restrict__ Wvp,
                            bf16* __restrict__ W1p, bf16* __restrict__ W2p,
                            float* __restrict__ bnsc, float* __restrict__ bnsh)
{
  const size_t SQ = (size_t)16 * 48 * 512;
  const size_t S1 = (size_t)16 * KS1 * 512;
  const size_t S2 = (size_t)32 * 512;
  const size_t total = 3 * SQ + S1 + S2;
  size_t e = (size_t)blockIdx.x * 256 + threadIdx.x;
  if (e < total) {
    const float* src; bf16* dst; size_t idx; int KS, Ksrc, Ncol;
    if (e < SQ)              { src = Wq; dst = Wqp; idx = e;              KS = 48;  Ksrc = 768;  Ncol = 512; }
    else if (e < 2 * SQ)     { src = Wk; dst = Wkp; idx = e - SQ;         KS = 48;  Ksrc = 768;  Ncol = 512; }
    else if (e < 3 * SQ)     { src = Wv; dst = Wvp; idx = e - 2 * SQ;     KS = 48;  Ksrc = 768;  Ncol = 512; }
    else if (e < 3 * SQ + S1){ src = W1; dst = W1p; idx = e - 3 * SQ;     KS = KS1; Ksrc = 3074; Ncol = 512; }
    else                     { src = W2; dst = W2p; idx = e - 3 * SQ - S1;KS = 32;  Ksrc = 512;  Ncol = 32;  }
    size_t ctblk = (size_t)KS * 512;
    int ct = (int)(idx / ctblk);
    size_t rem = idx % ctblk;
    int ks = (int)(rem >> 9);
    int lrem = (int)(rem & 511);
    int lane = lrem >> 3, jj = lrem & 7;
    int k = ks * 16 + 8 * (lane >> 5) + jj;
    int n = ct * 32 + (lane & 31);
    float v = (k < Ksrc) ? src[(size_t)k * Ncol + n] : 0.f;
    dst[idx] = (bf16)v;
  }
  if (e < 32) {
    float rs = rsqrtf(var[e] + 1e-5f);
    float s = gamma[e] * rs;
    bnsc[e] = s;
    bnsh[e] = (b2[e] - mean[e]) * s + beta[e];
  }
}

// ---------------------------------------------------------------------------
// proj v13: wide-N (128 rows x 512 cols, 512 thr, 8 waves), 2 BLOCKS/CU.
// A: global fp32 -> depth-2 register stash -> cvt bf16 -> one ds_write_b128
// into fragment-direct layout (granule == tid; zero conflicts), A dbuf 16KB.
// B (32x512 frag-direct bf16, 32KB) staged via global_load_lds, DOUBLE-
// buffered: B(t+1) staged during step t (intra-step coverage ~thousands of
// cycles >> L2 latency). LDS = 80KB -> 2 blocks/CU: when one block drains at
// its barrier, the other block's waves keep the MFMA pipe fed (the lockstep
// stall that pinned every 1-block variant at ~21% MfmaUtil).
// vmcnt ledger at end of step t: PWRITE_A implicit vmcnt(6); explicit
// vmcnt(2) retires B(t+1), keeps A(t+2)'s 2 loads in flight (never 0).
// Grid: 3 jobs (q,k,v) x 1024 mstrips; XCD-aware (bi&7 = XCD).
// v is written TRANSPOSED per batch: vT[b][p][m].
// ---------------------------------------------------------------------------

#define NSTEP 24  // K=768 / BK=32

#define AS1 __attribute__((address_space(1)))
#define AS3 __attribute__((address_space(3)))

// issue A k-chunk t into stash pfS: thread (ar32,aksl,ahl,aln) loads 8 fp32
// of row (row0+ar32*32+aln), cols t*32 + aksl*16 + ahl*8.
#define ISSUE_A(t, pfS) do {                                                   \
  const float* s_ = Asel + (size_t)(row0 + ar32 * 32 + aln) * 768              \
                    + (t) * 32 + aksl * 16 + ahl * 8;                          \
  pfS[0] = *(const f32x4*)s_;                                                  \
  pfS[1] = *(const f32x4*)(s_ + 4);                                            \
} while (0)

// cvt + single ds_write_b128; LDS granule == tid (frag-direct, conflict-free)
#define PWRITE_A(pfS, b2) do {                                                 \
  bf16x8 v_;                                                                   \
  _Pragma("unroll")                                                            \
  for (int q_ = 0; q_ < 4; q_++) { v_[q_] = (bf16)pfS[0][q_]; v_[4 + q_] = (bf16)pfS[1][q_]; } \
  *(bf16x8*)((char*)Ab[b2] + tid * 16) = v_;                                   \
} while (0)

// stage B k-chunk t (32 k x 512 cols, frag-direct) into Bb[b2]: 4 DMAs/thread
#define PSTAGE_B(t, b2) do {                                                   \
  _Pragma("unroll")                                                            \
  for (int i_ = 0; i_ < 4; i_++) {                                             \
    int c_ = wid * 4 + i_;              /* 0..31 */                            \
    int ct_ = c_ >> 1, ksl_ = c_ & 1;                                          \
    const bf16* src_ = Wp + ((size_t)(ct_ * 48 + (t) * 2 + ksl_) * 64 + lane) * 8; \
    __builtin_amdgcn_global_load_lds(                                          \
      (const AS1 unsigned int*)src_,                                           \
      (AS3 unsigned int*)((char*)Bb[b2] + c_ * 1024), 16, 0, 0);               \
  }                                                                            \
} while (0)

// A fragment: one conflict-free ds_read_b128
#define PFRAG(dst, b2, r32_, ksl_) do {                                        \
  dst = *(const bf16x8*)((const char*)Ab[b2] +                                 \
        (((((r32_) * 2 + (ksl_)) * 2 + hl) * 32) + ln) * 16);                  \
} while (0)

// compute tile t: 2 ksl x (2 A-frags + 4 B-frags x 2 accs) = 16 MFMA/wave
#define PCOMPUTE(b2a, b2b) do {                                                \
  _Pragma("unroll")                                                            \
  for (int ksl_ = 0; ksl_ < 2; ksl_++) {                                       \
    bf16x8 x0_, x1_;                                                           \
    PFRAG(x0_, b2a, wr * 2 + 0, ksl_);                                         \
    PFRAG(x1_, b2a, wr * 2 + 1, ksl_);                                         \
    _Pragma("unroll")                                                          \
    for (int c4_ = 0; c4_ < 4; c4_++) {                                        \
      bf16x8 y_ = *(const bf16x8*)((const char*)Bb[b2b] +                      \
                   (((wc4 * 4 + c4_) * 2 + ksl_) * 1024) + lane * 16);         \
      acc0[c4_] = mfma16(x0_, y_, acc0[c4_]);                                  \
      acc1[c4_] = mfma16(x1_, y_, acc1[c4_]);                                  \
    }                                                                          \
  }                                                                            \
} while (0)

// step t: issue A(t+2) into slot freed last step + stage B(t+1) DMAs,
// compute t, write A(t+1) from slot filled last step (implicit vmcnt(6)),
// explicit vmcnt(2) retires B(t+1) keeping A(t+2) in flight, barrier.
#define PSTEP(t, pfWr, pfIs) do {                                              \
  if ((t) + 2 < NSTEP) { ISSUE_A((t) + 2, pfIs); }                             \
  if ((t) + 1 < NSTEP) { PSTAGE_B((t) + 1, ((t) + 1) & 1); }                   \
  __builtin_amdgcn_sched_barrier(0);                                           \
  PCOMPUTE((t) & 1, (t) & 1);                                                  \
  if ((t) + 1 < NSTEP) {                                                       \
    PWRITE_A(pfWr, ((t) + 1) & 1);                                             \
    if ((t) + 2 < NSTEP) { asm volatile("s_waitcnt vmcnt(2)" ::: "memory"); }  \
    else                 { asm volatile("s_waitcnt vmcnt(0)" ::: "memory"); }  \
    asm volatile("s_waitcnt lgkmcnt(0)" ::: "memory");                         \
    __builtin_amdgcn_s_barrier();                                              \
    __builtin_amdgcn_sched_barrier(0);                                         \
  }                                                                            \
} while (0)

__global__ __launch_bounds__(512, 4)
void proj_kernel(const float* __restrict__ content, const float* __restrict__ image,
                 const bf16* __restrict__ Wqp, const bf16* __restrict__ Wkp,
                 const bf16* __restrict__ Wvp,
                 const float* __restrict__ bq, const float* __restrict__ bk,
                 const float* __restrict__ bv,
                 bf16* __restrict__ qbuf, bf16* __restrict__ kbuf, bf16* __restrict__ vTbuf)
{
  __shared__ bf16 Ab[2][4096];     // 2 x 8KB bf16 A chunks (frag-direct)
  __shared__ bf16 Bb[2][16384];    // 2 x 32KB frag-direct B chunks (80KB total)

  const int bi = blockIdx.x;
  const int xc = bi & 7;
  const int j  = bi >> 3;          // [0, 384)
  const int mstrip = xc * 128 + j / 3;
  const int t = j % 3;

  const float* Asel; const bf16* Wp; const float* bias; bf16* outp;
  int vmode;
  if (t == 0)      { Asel = content; Wp = Wqp; bias = bq; outp = qbuf;  vmode = 0; }
  else if (t == 1) { Asel = image;   Wp = Wkp; bias = bk; outp = kbuf;  vmode = 0; }
  else             { Asel = image;   Wp = Wvp; bias = bv; outp = vTbuf; vmode = 1; }

  const int row0 = mstrip * 128;
  const int tid = threadIdx.x;
  const int wid = tid >> 6, lane = tid & 63, hl = lane >> 5, ln = lane & 31;
  const int wr = wid >> 2, wc4 = wid & 3;   // row-half, col-quarter

  // A-staging role of this thread (granule == tid)
  const int ar32 = wid >> 1;       // row tile 0..3
  const int aksl = wid & 1;        // k slice 0..1
  const int ahl  = hl;             // k half-of-slice
  const int aln  = ln;             // row-in-tile

  // hoist bias loads (oldest VMEM; retired at the first implicit drain)
  float bsv[4];
#pragma unroll
  for (int c4 = 0; c4 < 4; c4++) bsv[c4] = bias[wc4 * 128 + c4 * 32 + ln];
  __builtin_amdgcn_sched_barrier(0);

  f32x16 acc0[4], acc1[4];
#pragma unroll
  for (int c4 = 0; c4 < 4; c4++) { acc0[c4] = zero16(); acc1[c4] = zero16(); }

  f32x4 pfA0[2], pfA1[2];   // depth-2 A stash: tile i in slot i&1

  // prologue: A(0)->slot0, A(1)->slot1, B(0) DMAs; PWRITE_A(slot0) implicitly
  // waits vmcnt(6) (retires bias+A(0), keeps A(1)+B(0) in flight); explicit
  // vmcnt(2) retires B(0) (A(1) stays in flight); barrier publishes Ab0/Bb0.
  ISSUE_A(0, pfA0);
  ISSUE_A(1, pfA1);
  PSTAGE_B(0, 0);
  __builtin_amdgcn_sched_barrier(0);
  PWRITE_A(pfA0, 0);
  asm volatile("s_waitcnt vmcnt(2)" ::: "memory");
  asm volatile("s_waitcnt lgkmcnt(0)" ::: "memory");
  __builtin_amdgcn_s_barrier();
  __builtin_amdgcn_sched_barrier(0);

  // tile i in stash slot i&1: pfWr = slot[(t+1)&1], pfIs = slot[t&1]
  PSTEP(0,  pfA1, pfA0);  PSTEP(1,  pfA0, pfA1);  PSTEP(2,  pfA1, pfA0);
  PSTEP(3,  pfA0, pfA1);  PSTEP(4,  pfA1, pfA0);  PSTEP(5,  pfA0, pfA1);
  PSTEP(6,  pfA1, pfA0);  PSTEP(7,  pfA0, pfA1);  PSTEP(8,  pfA1, pfA0);
  PSTEP(9,  pfA0, pfA1);  PSTEP(10, pfA1, pfA0);  PSTEP(11, pfA0, pfA1);
  PSTEP(12, pfA1, pfA0);  PSTEP(13, pfA0, pfA1);  PSTEP(14, pfA1, pfA0);
  PSTEP(15, pfA0, pfA1);  PSTEP(16, pfA1, pfA0);  PSTEP(17, pfA0, pfA1);
  PSTEP(18, pfA1, pfA0);  PSTEP(19, pfA0, pfA1);  PSTEP(20, pfA1, pfA0);
  PSTEP(21, pfA0, pfA1);  PSTEP(22, pfA1, pfA0);  PSTEP(23, pfA0, pfA1);

  // epilogue: C/D layout col=lane&31, row=(reg&3)+8*(reg>>2)+4*(lane>>5)
#pragma unroll
  for (int c4 = 0; c4 < 4; c4++) {
    const int n = wc4 * 128 + c4 * 32 + ln;
    const float bs = bsv[c4];
#pragma unroll
    for (int rt = 0; rt < 2; rt++) {
      f32x16 a = (rt == 0) ? acc0[c4] : acc1[c4];
      const int rowbase = row0 + wr * 64 + rt * 32;
      if (vmode == 0) {
#pragma unroll
        for (int r = 0; r < 16; r++) {
          int rp = (r & 3) + 8 * (r >> 2) + 4 * hl;
          outp[(size_t)(rowbase + rp) * 512 + n] = (bf16)(a[r] + bs);
        }
      } else {
        const int bidx = rowbase >> 5;   // 32-row groups == one batch
#pragma unroll
        for (int g = 0; g < 4; g++) {
          int m0 = g * 8 + 4 * hl;
          bf16x4 pk;
#pragma unroll
          for (int q2 = 0; q2 < 4; q2++) pk[q2] = (bf16)(a[g * 4 + q2] + bs);
          *(bf16x4*)(vTbuf + ((size_t)bidx * 512 + n) * 32 + m0) = pk;
        }
      }
    }
  }
}

// ---------------------------------------------------------------------------
// attn: one block per batch. scores (split-K MFMA) -> softmax -> align (MFMA on
// vT) -> features (q,align,sub,dot) -> mean/max pool -> pooled[b][3136] bf16.
// q/k/vT read straight from global (L2-hot, 96KB/batch); only ~24KB LDS.
// ---------------------------------------------------------------------------
__global__ __launch_bounds__(256, 4)
void attn_kernel(const bf16* __restrict__ qbuf, const bf16* __restrict__ kbuf,
                 const bf16* __restrict__ vTbuf, bf16* __restrict__ pooled)
{
  __shared__ float scp[4][32][33];
  __shared__ float sc[32][33];
  __shared__ bf16  attn_s[32][32];
  __shared__ float dot_s[32];

  const int b = blockIdx.x;
  const int tid = threadIdx.x;
  const int wid = tid >> 6, lane = tid & 63, hl = lane >> 5, ln = lane & 31;

  const bf16* qb = qbuf + (size_t)b * 32 * 512;
  const bf16* kb = kbuf + (size_t)b * 32 * 512;
  const bf16* vb = vTbuf + (size_t)b * 512 * 32;
  bf16* pb = pooled + (size_t)b * KPAD;

  if (tid < 32) dot_s[tid] = 0.f;

  // scores partials: wave w covers K-steps [w*8, w*8+8)
  f32x16 acc = zero16();
#pragma unroll
  for (int s8 = 0; s8 < 8; s8++) {
    int kk = wid * 8 + s8;
    int o = ln * 512 + kk * 16 + hl * 8;
    bf16x8 aq  = *(const bf16x8*)(qb + o);
    bf16x8 bk2 = *(const bf16x8*)(kb + o);
    acc = mfma16(aq, bk2, acc);
  }
#pragma unroll
  for (int r = 0; r < 16; r++) {
    int rp = (r & 3) + 8 * (r >> 2) + 4 * hl;
    scp[wid][rp][ln] = acc[r];
  }
  __syncthreads();
  for (int e = tid; e < 1024; e += 256) {
    int rr = e >> 5, mm = e & 31;
    sc[rr][mm] = (scp[0][rr][mm] + scp[1][rr][mm] + scp[2][rr][mm] + scp[3][rr][mm])
                 * 0.04419417382415922f;  // 1/sqrt(512)
  }
  __syncthreads();
  if (tid < 32) {
    float mx = -1e30f;
    for (int m = 0; m < 32; m++) mx = fmaxf(mx, sc[tid][m]);
    float sum = 0.f;
    for (int m = 0; m < 32; m++) { float ex = __expf(sc[tid][m] - mx); sum += ex; sc[tid][m] = ex; }
    float inv = 1.f / sum;
    for (int m = 0; m < 32; m++) attn_s[tid][m] = (bf16)(sc[tid][m] * inv);
  }
  __syncthreads();

  // align: A = attn (LDS), B = vT rows (global, contiguous 16B frags)
  bf16x8 pa0 = *(const bf16x8*)((const char*)attn_s + ln * 64 + hl * 16);
  bf16x8 pa1 = *(const bf16x8*)((const char*)attn_s + ln * 64 + 32 + hl * 16);

  float dacc[16];
#pragma unroll
  for (int i = 0; i < 16; i++) dacc[i] = 0.f;

  for (int cc = 0; cc < 4; cc++) {
    int ct = wid * 4 + cc;
    int p = ct * 32 + ln;
    f32x16 av = zero16();
    bf16x8 v0 = *(const bf16x8*)(vb + p * 32 + hl * 8);
    bf16x8 v1 = *(const bf16x8*)(vb + p * 32 + 16 + hl * 8);
    av = mfma16(pa0, v0, av);
    av = mfma16(pa1, v1, av);

    float sq = 0.f, sa = 0.f, ss = 0.f;
    float mq = -1e30f, ma = -1e30f, ms = -1e30f;
#pragma unroll
    for (int r = 0; r < 16; r++) {
      int rp = (r & 3) + 8 * (r >> 2) + 4 * hl;
      float qv = (float)qb[rp * 512 + p];
      float al = av[r];
      float sb = qv - al;
      sq += qv; sa += al; ss += sb;
      mq = fmaxf(mq, qv); ma = fmaxf(ma, al); ms = fmaxf(ms, sb);
      dacc[r] += qv * al;
    }
    // combine the two half-wave r-sets (lanes l and l^32 hold the same p)
    sq += __shfl_xor(sq, 32); sa += __shfl_xor(sa, 32); ss += __shfl_xor(ss, 32);
    mq = fmaxf(mq, __shfl_xor(mq, 32));
    ma = fmaxf(ma, __shfl_xor(ma, 32));
    ms = fmaxf(ms, __shfl_xor(ms, 32));
    if (lane < 32) {
      pb[p]        = (bf16)(sq * (1.f / 32.f));
      pb[512 + p]  = (bf16)(sa * (1.f / 32.f));
      pb[1024 + p] = (bf16)(ss * (1.f / 32.f));
      pb[1537 + p] = (bf16)mq;
      pb[2049 + p] = (bf16)ma;
      pb[2561 + p] = (bf16)ms;
    }
  }
  // dot[r] = sum_p q*align : butterfly over the 32-lane half, then LDS atomics
#pragma unroll
  for (int off = 1; off <= 16; off <<= 1) {
#pragma unroll
    for (int i = 0; i < 16; i++) dacc[i] += __shfl_xor(dacc[i], off);
  }
  if (ln == 0) {
#pragma unroll
    for (int i = 0; i < 16; i++) {
      int rp = (i & 3) + 8 * (i >> 2) + 4 * hl;
      atomicAdd(&dot_s[rp], dacc[i]);
    }
  }
  __syncthreads();
  if (tid < 32) {
    float d = dot_s[tid];
    float sm = d, mx = d;
#pragma unroll
    for (int off = 1; off <= 16; off <<= 1) {
      sm += __shfl_xor(sm, off);
      mx = fmaxf(mx, __shfl_xor(mx, off));
    }
    if (tid == 0) {
      pb[1536] = (bf16)(sm * (1.f / 32.f));
      pb[3073] = (bf16)mx;
    }
  }
  for (int z = tid; z < KPAD - 3074; z += 256) pb[3074 + z] = (bf16)0.f;
}

// ---------------------------------------------------------------------------
// ffn1: h = relu(pooled @ W1 + b1)   [4096 x 3136] @ [3136 x 512] -> bf16
// ---------------------------------------------------------------------------
__global__ __launch_bounds__(256, 2)
void ffn1_kernel(const bf16* __restrict__ pooled, const bf16* __restrict__ W1p,
                 const float* __restrict__ b1, bf16* __restrict__ hbuf)
{
  __shared__ bf16 At[2][128 * 64];
  const int bi = blockIdx.x;
  const int mstrip = bi >> 2, nstrip = bi & 3;
  const int row0 = mstrip * 128;
  const int tid = threadIdx.x;
  const int wid = tid >> 6, lane = tid & 63, hl = lane >> 5, ln = lane & 31;
  const int wr = wid >> 1, wc = wid & 1;

  const bf16* Wb0 = W1p + (size_t)(nstrip * 4 + wc * 2 + 0) * (KS1 * 512);
  const bf16* Wb1 = W1p + (size_t)(nstrip * 4 + wc * 2 + 1) * (KS1 * 512);

  f32x16 a00 = zero16(), a01 = zero16(), a10 = zero16(), a11 = zero16();

#pragma unroll
  for (int i = 0; i < 4; i++) {
    int s = tid + 256 * i;
    int r = s >> 3, c8 = s & 7;
    u32x4 tv = *(const u32x4*)(pooled + (size_t)(row0 + r) * KPAD + c8 * 8);
    *(u32x4*)((char*)At[0] + swz(r, c8 * 16)) = tv;
  }
  __syncthreads();

  u32x4 pf[4];
  for (int kc = 0; kc < 49; kc++) {
    const int cur = kc & 1;
    if (kc < 48) {
#pragma unroll
      for (int i = 0; i < 4; i++) {
        int s = tid + 256 * i;
        int r = s >> 3, c8 = s & 7;
        pf[i] = *(const u32x4*)(pooled + (size_t)(row0 + r) * KPAD + (kc + 1) * 64 + c8 * 8);
      }
    }
#pragma unroll
    for (int ks = 0; ks < 4; ks++) {
      const char* base = (const char*)At[cur];
      bf16x8 x0 = *(const bf16x8*)(base + swz(wr * 64 + ln,      ks * 32 + hl * 16));
      bf16x8 x1 = *(const bf16x8*)(base + swz(wr * 64 + 32 + ln, ks * 32 + hl * 16));
      size_t wo = ((size_t)(kc * 4 + ks) * 64 + lane) * 8;
      bf16x8 y0 = *(const bf16x8*)(Wb0 + wo);
      bf16x8 y1 = *(const bf16x8*)(Wb1 + wo);
      a00 = mfma16(x0, y0, a00); a01 = mfma16(x0, y1, a01);
      a10 = mfma16(x1, y0, a10); a11 = mfma16(x1, y1, a11);
    }
    if (kc < 48) {
#pragma unroll
      for (int i = 0; i < 4; i++) {
        int s = tid + 256 * i;
        int r = s >> 3, c8 = s & 7;
        *(u32x4*)((char*)At[cur ^ 1] + swz(r, c8 * 16)) = pf[i];
      }
    }
    __syncthreads();
  }

#pragma unroll
  for (int cc = 0; cc < 2; cc++) {
    const int n = nstrip * 128 + wc * 64 + cc * 32 + ln;
    const float bb = b1[n];
#pragma unroll
    for (int rc = 0; rc < 2; rc++) {
      f32x16 a = (cc == 0) ? (rc == 0 ? a00 : a10) : (rc == 0 ? a01 : a11);
      const int rowbase = row0 + wr * 64 + rc * 32;
#pragma unroll
      for (int r = 0; r < 16; r++) {
        int rp = (r & 3) + 8 * (r >> 2) + 4 * hl;
        hbuf[(size_t)(rowbase + rp) * 512 + n] = (bf16)fmaxf(a[r] + bb, 0.f);
      }
    }
  }
}

// ---------------------------------------------------------------------------
// ffn2: y = (h @ W2) * bnsc + bnsh   [4096 x 512] @ [512 x 32] -> fp32 out
// ---------------------------------------------------------------------------
__global__ __launch_bounds__(256, 2)
void ffn2_kernel(const bf16* __restrict__ hbuf, const bf16* __restrict__ W2p,
                 const float* __restrict__ bnsc, const float* __restrict__ bnsh,
                 float* __restrict__ out)
{
  __shared__ bf16 At[2][128 * 64];
  const int row0 = blockIdx.x * 128;
  const int tid = threadIdx.x;
  const int wid = tid >> 6, lane = tid & 63, hl = lane >> 5, ln = lane & 31;

  f32x16 a0 = zero16();

#pragma unroll
  for (int i = 0; i < 4; i++) {
    int s = tid + 256 * i;
    int r = s >> 3, c8 = s & 7;
    u32x4 tv = *(const u32x4*)(hbuf + (size_t)(row0 + r) * 512 + c8 * 8);
    *(u32x4*)((char*)At[0] + swz(r, c8 * 16)) = tv;
  }
  __syncthreads();

  u32x4 pf[4];
  for (int kc = 0; kc < 8; kc++) {
    const int cur = kc & 1;
    if (kc < 7) {
#pragma unroll
      for (int i = 0; i < 4; i++) {
        int s = tid + 256 * i;
        int r = s >> 3, c8 = s & 7;
        pf[i] = *(const u32x4*)(hbuf + (size_t)(row0 + r) * 512 + (kc + 1) * 64 + c8 * 8);
      }
    }
#pragma unroll
    for (int ks = 0; ks < 4; ks++) {
      const char* base = (const char*)At[cur];
      bf16x8 x0 = *(const bf16x8*)(base + swz(wid * 32 + ln, ks * 32 + hl * 16));
      bf16x8 y0 = *(const bf16x8*)(W2p + ((size_t)(kc * 4 + ks) * 64 + lane) * 8);
      a0 = mfma16(x0, y0, a0);
    }
    if (kc < 7) {
#pragma unroll
      for (int i = 0; i < 4; i++) {
        int s = tid + 256 * i;
        int r = s >> 3, c8 = s & 7;
        *(u32x4*)((char*)At[cur ^ 1] + swz(r, c8 * 16)) = pf[i];
      }
    }
    __syncthreads();
  }

  const float scl = bnsc[ln], sft = bnsh[ln];
#pragma unroll
  for (int r = 0; r < 16; r++) {
    int rp = (r & 3) + 8 * (r >> 2) + 4 * hl;
    out[(size_t)(row0 + wid * 32 + rp) * 32 + ln] = a0[r] * scl + sft;
  }
}

// ---------------------------------------------------------------------------
extern "C" void kernel_launch(void* const* d_in, const int* in_sizes, int n_in,
                              void* d_out, int out_size, void* d_ws, size_t ws_size,
                              hipStream_t stream)
{
  const float* content = (const float*)d_in[0];
  const float* image   = (const float*)d_in[1];
  const float* Wq = (const float*)d_in[2];
  const float* bq = (const float*)d_in[3];
  const float* Wk = (const float*)d_in[4];
  const float* bk = (const float*)d_in[5];
  const float* Wv = (const float*)d_in[6];
  const float* bv = (const float*)d_in[7];
  const float* W1 = (const float*)d_in[8];
  const float* b1 = (const float*)d_in[9];
  const float* W2 = (const float*)d_in[10];
  const float* b2 = (const float*)d_in[11];
  const float* gamma = (const float*)d_in[12];
  const float* beta  = (const float*)d_in[13];
  const float* mean  = (const float*)d_in[14];
  const float* var   = (const float*)d_in[15];
  float* out = (float*)d_out;

  char* ws = (char*)d_ws;
  size_t off = 0;
  auto alloc = [&](size_t bytes) { char* p = ws + off; off += bytes; return p; };
  bf16* qbuf   = (bf16*)alloc((size_t)131072 * 512 * 2);
  bf16* kbuf   = (bf16*)alloc((size_t)131072 * 512 * 2);
  bf16* vTbuf  = (bf16*)alloc((size_t)131072 * 512 * 2);
  bf16* pooled = (bf16*)alloc((size_t)4096 * KPAD * 2);
  bf16* hbuf   = (bf16*)alloc((size_t)4096 * 512 * 2);
  bf16* Wqp    = (bf16*)alloc((size_t)768 * 512 * 2);
  bf16* Wkp    = (bf16*)alloc((size_t)768 * 512 * 2);
  bf16* Wvp    = (bf16*)alloc((size_t)768 * 512 * 2);
  bf16* W1p    = (bf16*)alloc((size_t)KPAD * 512 * 2);
  bf16* W2p    = (bf16*)alloc((size_t)512 * 32 * 2);
  float* bnsc  = (float*)alloc(128);
  float* bnsh  = (float*)alloc(128);
  if (ws_size < off) return;  // signals cleanly via absmax if ws is too small

  prep_kernel<<<10944, 256, 0, stream>>>(Wq, Wk, Wv, W1, W2, b2, gamma, beta, mean, var,
                                         Wqp, Wkp, Wvp, W1p, W2p, bnsc, bnsh);
  proj_kernel<<<3072, 512, 0, stream>>>(content, image, Wqp, Wkp, Wvp, bq, bk, bv,
                                        qbuf, kbuf, vTbuf);
  attn_kernel<<<4096, 256, 0, stream>>>(qbuf, kbuf, vTbuf, pooled);
  ffn1_kernel<<<128, 256, 0, stream>>>(pooled, W1p, b1, hbuf);
  ffn2_kernel<<<32, 256, 0, stream>>>(hbuf, W2p, bnsc, bnsh, out);
}

// Round 14
// 878.815 us; speedup vs baseline: 7.5531x; 7.5531x over previous
//
#include <hip/hip_runtime.h>
#include <hip/hip_bf16.h>
#include <cstdint>

typedef __bf16 bf16;
typedef __attribute__((ext_vector_type(8)))  __bf16 bf16x8;
typedef __attribute__((ext_vector_type(4)))  __bf16 bf16x4;
typedef __attribute__((ext_vector_type(16))) float  f32x16;
typedef __attribute__((ext_vector_type(4)))  float  f32x4;
typedef __attribute__((ext_vector_type(4)))  unsigned int u32x4;

#define KPAD 3136   // FFN K (3074) padded to 49*64
#define KS1  196    // KPAD/16

__device__ __forceinline__ f32x16 zero16() {
  f32x16 z;
#pragma unroll
  for (int i = 0; i < 16; i++) z[i] = 0.f;
  return z;
}

__device__ __forceinline__ f32x16 mfma16(bf16x8 a, bf16x8 b, f32x16 c) {
  return __builtin_amdgcn_mfma_f32_32x32x16_bf16(a, b, c, 0, 0, 0);
}

// XOR swizzle for [rows][64] bf16 LDS tiles (row stride 128B) — used by ffn1/2.
__device__ __forceinline__ unsigned swz(unsigned row, unsigned bir) {
  return row * 128u + (bir ^ ((row & 7u) << 4));
}

// ---------------------------------------------------------------------------
// prep: pack weights into fragment-direct layout  packed[((ct*KS+ks)*64+lane)*8+j]
//       = W[ks*16 + 8*(lane>>5) + j][ct*32 + (lane&31)]   (zero-padded K for W1)
//       + fold BatchNorm (+b2) into per-col scale/shift.
// ---------------------------------------------------------------------------
__global__ void prep_kernel(const float* __restrict__ Wq, const float* __restrict__ Wk,
                            const float* __restrict__ Wv, const float* __restrict__ W1,
                            const float* __restrict__ W2, const float* __restrict__ b2,
                            const float* __restrict__ gamma, const float* __restrict__ beta,
                            const float* __restrict__ mean, const float* __restrict__ var,
                            bf16* __restrict__ Wqp, bf16* __restrict__ Wkp, bf16* __restrict__ Wvp,
                            bf16* __restrict__ W1p, bf16* __restrict__ W2p,
                            float* __restrict__ bnsc, float* __restrict__ bnsh)
{
  const size_t SQ = (size_t)16 * 48 * 512;
  const size_t S1 = (size_t)16 * KS1 * 512;
  const size_t S2 = (size_t)32 * 512;
  const size_t total = 3 * SQ + S1 + S2;
  size_t e = (size_t)blockIdx.x * 256 + threadIdx.x;
  if (e < total) {
    const float* src; bf16* dst; size_t idx; int KS, Ksrc, Ncol;
    if (e < SQ)              { src = Wq; dst = Wqp; idx = e;              KS = 48;  Ksrc = 768;  Ncol = 512; }
    else if (e < 2 * SQ)     { src = Wk; dst = Wkp; idx = e - SQ;         KS = 48;  Ksrc = 768;  Ncol = 512; }
    else if (e < 3 * SQ)     { src = Wv; dst = Wvp; idx = e - 2 * SQ;     KS = 48;  Ksrc = 768;  Ncol = 512; }
    else if (e < 3 * SQ + S1){ src = W1; dst = W1p; idx = e - 3 * SQ;     KS = KS1; Ksrc = 3074; Ncol = 512; }
    else                     { src = W2; dst = W2p; idx = e - 3 * SQ - S1;KS = 32;  Ksrc = 512;  Ncol = 32;  }
    size_t ctblk = (size_t)KS * 512;
    int ct = (int)(idx / ctblk);
    size_t rem = idx % ctblk;
    int ks = (int)(rem >> 9);
    int lrem = (int)(rem & 511);
    int lane = lrem >> 3, jj = lrem & 7;
    int k = ks * 16 + 8 * (lane >> 5) + jj;
    int n = ct * 32 + (lane & 31);
    float v = (k < Ksrc) ? src[(size_t)k * Ncol + n] : 0.f;
    dst[idx] = (bf16)v;
  }
  if (e < 32) {
    float rs = rsqrtf(var[e] + 1e-5f);
    float s = gamma[e] * rs;
    bnsc[e] = s;
    bnsh[e] = (b2[e] - mean[e]) * s + beta[e];
  }
}

// ---------------------------------------------------------------------------
// proj v14: wide-N (128 rows x 512 cols, 512 thr, 8 waves), 2 BLOCKS/CU via
// the LDS budget (80KB x 2 = 160KB), NOT via launch-bounds VGPR capping --
// R13's __launch_bounds__(512,4) capped VGPRs at 64 and spilled the 128-VGPR
// accumulator to scratch (17.9GB writes, 10x slowdown). (512,2) keeps the
// 256-VGPR budget (kernel needs ~108, no spill) and the HW still co-resides
// 2 blocks/CU because LDS and wave slots fit.
// A: global fp32 -> depth-2 register stash -> cvt bf16 -> one ds_write_b128
// into fragment-direct layout (granule == tid; zero conflicts), A dbuf 16KB.
// B (32x512 frag-direct bf16, 32KB) staged via global_load_lds, double-
// buffered: B(t+1) staged during step t. vmcnt ledger at end of step t:
// PWRITE_A implicit vmcnt(6); explicit vmcnt(2) retires B(t+1), keeps
// A(t+2)'s 2 loads in flight (never 0 in-loop).
// Grid: 3 jobs (q,k,v) x 1024 mstrips; XCD-aware (bi&7 = XCD).
// v is written TRANSPOSED per batch: vT[b][p][m].
// ---------------------------------------------------------------------------

#define NSTEP 24  // K=768 / BK=32

#define AS1 __attribute__((address_space(1)))
#define AS3 __attribute__((address_space(3)))

// issue A k-chunk t into stash pfS: thread (ar32,aksl,ahl,aln) loads 8 fp32
// of row (row0+ar32*32+aln), cols t*32 + aksl*16 + ahl*8.
#define ISSUE_A(t, pfS) do {                                                   \
  const float* s_ = Asel + (size_t)(row0 + ar32 * 32 + aln) * 768              \
                    + (t) * 32 + aksl * 16 + ahl * 8;                          \
  pfS[0] = *(const f32x4*)s_;                                                  \
  pfS[1] = *(const f32x4*)(s_ + 4);                                            \
} while (0)

// cvt + single ds_write_b128; LDS granule == tid (frag-direct, conflict-free)
#define PWRITE_A(pfS, b2) do {                                                 \
  bf16x8 v_;                                                                   \
  _Pragma("unroll")                                                            \
  for (int q_ = 0; q_ < 4; q_++) { v_[q_] = (bf16)pfS[0][q_]; v_[4 + q_] = (bf16)pfS[1][q_]; } \
  *(bf16x8*)((char*)Ab[b2] + tid * 16) = v_;                                   \
} while (0)

// stage B k-chunk t (32 k x 512 cols, frag-direct) into Bb[b2]: 4 DMAs/thread
#define PSTAGE_B(t, b2) do {                                                   \
  _Pragma("unroll")                                                            \
  for (int i_ = 0; i_ < 4; i_++) {                                             \
    int c_ = wid * 4 + i_;              /* 0..31 */                            \
    int ct_ = c_ >> 1, ksl_ = c_ & 1;                                          \
    const bf16* src_ = Wp + ((size_t)(ct_ * 48 + (t) * 2 + ksl_) * 64 + lane) * 8; \
    __builtin_amdgcn_global_load_lds(                                          \
      (const AS1 unsigned int*)src_,                                           \
      (AS3 unsigned int*)((char*)Bb[b2] + c_ * 1024), 16, 0, 0);               \
  }                                                                            \
} while (0)

// A fragment: one conflict-free ds_read_b128
#define PFRAG(dst, b2, r32_, ksl_) do {                                        \
  dst = *(const bf16x8*)((const char*)Ab[b2] +                                 \
        (((((r32_) * 2 + (ksl_)) * 2 + hl) * 32) + ln) * 16);                  \
} while (0)

// compute tile t: 2 ksl x (2 A-frags + 4 B-frags x 2 accs) = 16 MFMA/wave
#define PCOMPUTE(b2a, b2b) do {                                                \
  _Pragma("unroll")                                                            \
  for (int ksl_ = 0; ksl_ < 2; ksl_++) {                                       \
    bf16x8 x0_, x1_;                                                           \
    PFRAG(x0_, b2a, wr * 2 + 0, ksl_);                                         \
    PFRAG(x1_, b2a, wr * 2 + 1, ksl_);                                         \
    _Pragma("unroll")                                                          \
    for (int c4_ = 0; c4_ < 4; c4_++) {                                        \
      bf16x8 y_ = *(const bf16x8*)((const char*)Bb[b2b] +                      \
                   (((wc4 * 4 + c4_) * 2 + ksl_) * 1024) + lane * 16);         \
      acc0[c4_] = mfma16(x0_, y_, acc0[c4_]);                                  \
      acc1[c4_] = mfma16(x1_, y_, acc1[c4_]);                                  \
    }                                                                          \
  }                                                                            \
} while (0)

// step t: issue A(t+2) into slot freed last step + stage B(t+1) DMAs,
// compute t, write A(t+1) from slot filled last step (implicit vmcnt(6)),
// explicit vmcnt(2) retires B(t+1) keeping A(t+2) in flight, barrier.
#define PSTEP(t, pfWr, pfIs) do {                                              \
  if ((t) + 2 < NSTEP) { ISSUE_A((t) + 2, pfIs); }                             \
  if ((t) + 1 < NSTEP) { PSTAGE_B((t) + 1, ((t) + 1) & 1); }                   \
  __builtin_amdgcn_sched_barrier(0);                                           \
  PCOMPUTE((t) & 1, (t) & 1);                                                  \
  if ((t) + 1 < NSTEP) {                                                       \
    PWRITE_A(pfWr, ((t) + 1) & 1);                                             \
    if ((t) + 2 < NSTEP) { asm volatile("s_waitcnt vmcnt(2)" ::: "memory"); }  \
    else                 { asm volatile("s_waitcnt vmcnt(0)" ::: "memory"); }  \
    asm volatile("s_waitcnt lgkmcnt(0)" ::: "memory");                         \
    __builtin_amdgcn_s_barrier();                                              \
    __builtin_amdgcn_sched_barrier(0);                                         \
  }                                                                            \
} while (0)

__global__ __launch_bounds__(512, 2)
void proj_kernel(const float* __restrict__ content, const float* __restrict__ image,
                 const bf16* __restrict__ Wqp, const bf16* __restrict__ Wkp,
                 const bf16* __restrict__ Wvp,
                 const float* __restrict__ bq, const float* __restrict__ bk,
                 const float* __restrict__ bv,
                 bf16* __restrict__ qbuf, bf16* __restrict__ kbuf, bf16* __restrict__ vTbuf)
{
  __shared__ bf16 Ab[2][4096];     // 2 x 8KB bf16 A chunks (frag-direct)
  __shared__ bf16 Bb[2][16384];    // 2 x 32KB frag-direct B chunks (80KB total)

  const int bi = blockIdx.x;
  const int xc = bi & 7;
  const int j  = bi >> 3;          // [0, 384)
  const int mstrip = xc * 128 + j / 3;
  const int t = j % 3;

  const float* Asel; const bf16* Wp; const float* bias; bf16* outp;
  int vmode;
  if (t == 0)      { Asel = content; Wp = Wqp; bias = bq; outp = qbuf;  vmode = 0; }
  else if (t == 1) { Asel = image;   Wp = Wkp; bias = bk; outp = kbuf;  vmode = 0; }
  else             { Asel = image;   Wp = Wvp; bias = bv; outp = vTbuf; vmode = 1; }

  const int row0 = mstrip * 128;
  const int tid = threadIdx.x;
  const int wid = tid >> 6, lane = tid & 63, hl = lane >> 5, ln = lane & 31;
  const int wr = wid >> 2, wc4 = wid & 3;   // row-half, col-quarter

  // A-staging role of this thread (granule == tid)
  const int ar32 = wid >> 1;       // row tile 0..3
  const int aksl = wid & 1;        // k slice 0..1
  const int ahl  = hl;             // k half-of-slice
  const int aln  = ln;             // row-in-tile

  // hoist bias loads (oldest VMEM; retired at the first implicit drain)
  float bsv[4];
#pragma unroll
  for (int c4 = 0; c4 < 4; c4++) bsv[c4] = bias[wc4 * 128 + c4 * 32 + ln];
  __builtin_amdgcn_sched_barrier(0);

  f32x16 acc0[4], acc1[4];
#pragma unroll
  for (int c4 = 0; c4 < 4; c4++) { acc0[c4] = zero16(); acc1[c4] = zero16(); }

  f32x4 pfA0[2], pfA1[2];   // depth-2 A stash: tile i in slot i&1

  // prologue: A(0)->slot0, A(1)->slot1, B(0) DMAs; PWRITE_A(slot0) implicitly
  // waits vmcnt(6) (retires bias+A(0), keeps A(1)+B(0) in flight); explicit
  // vmcnt(2) retires B(0) (A(1) stays in flight); barrier publishes Ab0/Bb0.
  ISSUE_A(0, pfA0);
  ISSUE_A(1, pfA1);
  PSTAGE_B(0, 0);
  __builtin_amdgcn_sched_barrier(0);
  PWRITE_A(pfA0, 0);
  asm volatile("s_waitcnt vmcnt(2)" ::: "memory");
  asm volatile("s_waitcnt lgkmcnt(0)" ::: "memory");
  __builtin_amdgcn_s_barrier();
  __builtin_amdgcn_sched_barrier(0);

  // tile i in stash slot i&1: pfWr = slot[(t+1)&1], pfIs = slot[t&1]
  PSTEP(0,  pfA1, pfA0);  PSTEP(1,  pfA0, pfA1);  PSTEP(2,  pfA1, pfA0);
  PSTEP(3,  pfA0, pfA1);  PSTEP(4,  pfA1, pfA0);  PSTEP(5,  pfA0, pfA1);
  PSTEP(6,  pfA1, pfA0);  PSTEP(7,  pfA0, pfA1);  PSTEP(8,  pfA1, pfA0);
  PSTEP(9,  pfA0, pfA1);  PSTEP(10, pfA1, pfA0);  PSTEP(11, pfA0, pfA1);
  PSTEP(12, pfA1, pfA0);  PSTEP(13, pfA0, pfA1);  PSTEP(14, pfA1, pfA0);
  PSTEP(15, pfA0, pfA1);  PSTEP(16, pfA1, pfA0);  PSTEP(17, pfA0, pfA1);
  PSTEP(18, pfA1, pfA0);  PSTEP(19, pfA0, pfA1);  PSTEP(20, pfA1, pfA0);
  PSTEP(21, pfA0, pfA1);  PSTEP(22, pfA1, pfA0);  PSTEP(23, pfA0, pfA1);

  // epilogue: C/D layout col=lane&31, row=(reg&3)+8*(reg>>2)+4*(lane>>5)
#pragma unroll
  for (int c4 = 0; c4 < 4; c4++) {
    const int n = wc4 * 128 + c4 * 32 + ln;
    const float bs = bsv[c4];
#pragma unroll
    for (int rt = 0; rt < 2; rt++) {
      f32x16 a = (rt == 0) ? acc0[c4] : acc1[c4];
      const int rowbase = row0 + wr * 64 + rt * 32;
      if (vmode == 0) {
#pragma unroll
        for (int r = 0; r < 16; r++) {
          int rp = (r & 3) + 8 * (r >> 2) + 4 * hl;
          outp[(size_t)(rowbase + rp) * 512 + n] = (bf16)(a[r] + bs);
        }
      } else {
        const int bidx = rowbase >> 5;   // 32-row groups == one batch
#pragma unroll
        for (int g = 0; g < 4; g++) {
          int m0 = g * 8 + 4 * hl;
          bf16x4 pk;
#pragma unroll
          for (int q2 = 0; q2 < 4; q2++) pk[q2] = (bf16)(a[g * 4 + q2] + bs);
          *(bf16x4*)(vTbuf + ((size_t)bidx * 512 + n) * 32 + m0) = pk;
        }
      }
    }
  }
}

// ---------------------------------------------------------------------------
// attn: one block per batch. scores (split-K MFMA) -> softmax -> align (MFMA on
// vT) -> features (q,align,sub,dot) -> mean/max pool -> pooled[b][3136] bf16.
// q/k/vT read straight from global (L2-hot, 96KB/batch); only ~24KB LDS.
// ---------------------------------------------------------------------------
__global__ __launch_bounds__(256, 4)
void attn_kernel(const bf16* __restrict__ qbuf, const bf16* __restrict__ kbuf,
                 const bf16* __restrict__ vTbuf, bf16* __restrict__ pooled)
{
  __shared__ float scp[4][32][33];
  __shared__ float sc[32][33];
  __shared__ bf16  attn_s[32][32];
  __shared__ float dot_s[32];

  const int b = blockIdx.x;
  const int tid = threadIdx.x;
  const int wid = tid >> 6, lane = tid & 63, hl = lane >> 5, ln = lane & 31;

  const bf16* qb = qbuf + (size_t)b * 32 * 512;
  const bf16* kb = kbuf + (size_t)b * 32 * 512;
  const bf16* vb = vTbuf + (size_t)b * 512 * 32;
  bf16* pb = pooled + (size_t)b * KPAD;

  if (tid < 32) dot_s[tid] = 0.f;

  // scores partials: wave w covers K-steps [w*8, w*8+8)
  f32x16 acc = zero16();
#pragma unroll
  for (int s8 = 0; s8 < 8; s8++) {
    int kk = wid * 8 + s8;
    int o = ln * 512 + kk * 16 + hl * 8;
    bf16x8 aq  = *(const bf16x8*)(qb + o);
    bf16x8 bk2 = *(const bf16x8*)(kb + o);
    acc = mfma16(aq, bk2, acc);
  }
#pragma unroll
  for (int r = 0; r < 16; r++) {
    int rp = (r & 3) + 8 * (r >> 2) + 4 * hl;
    scp[wid][rp][ln] = acc[r];
  }
  __syncthreads();
  for (int e = tid; e < 1024; e += 256) {
    int rr = e >> 5, mm = e & 31;
    sc[rr][mm] = (scp[0][rr][mm] + scp[1][rr][mm] + scp[2][rr][mm] + scp[3][rr][mm])
                 * 0.04419417382415922f;  // 1/sqrt(512)
  }
  __syncthreads();
  if (tid < 32) {
    float mx = -1e30f;
    for (int m = 0; m < 32; m++) mx = fmaxf(mx, sc[tid][m]);
    float sum = 0.f;
    for (int m = 0; m < 32; m++) { float ex = __expf(sc[tid][m] - mx); sum += ex; sc[tid][m] = ex; }
    float inv = 1.f / sum;
    for (int m = 0; m < 32; m++) attn_s[tid][m] = (bf16)(sc[tid][m] * inv);
  }
  __syncthreads();

  // align: A = attn (LDS), B = vT rows (global, contiguous 16B frags)
  bf16x8 pa0 = *(const bf16x8*)((const char*)attn_s + ln * 64 + hl * 16);
  bf16x8 pa1 = *(const bf16x8*)((const char*)attn_s + ln * 64 + 32 + hl * 16);

  float dacc[16];
#pragma unroll
  for (int i = 0; i < 16; i++) dacc[i] = 0.f;

  for (int cc = 0; cc < 4; cc++) {
    int ct = wid * 4 + cc;
    int p = ct * 32 + ln;
    f32x16 av = zero16();
    bf16x8 v0 = *(const bf16x8*)(vb + p * 32 + hl * 8);
    bf16x8 v1 = *(const bf16x8*)(vb + p * 32 + 16 + hl * 8);
    av = mfma16(pa0, v0, av);
    av = mfma16(pa1, v1, av);

    float sq = 0.f, sa = 0.f, ss = 0.f;
    float mq = -1e30f, ma = -1e30f, ms = -1e30f;
#pragma unroll
    for (int r = 0; r < 16; r++) {
      int rp = (r & 3) + 8 * (r >> 2) + 4 * hl;
      float qv = (float)qb[rp * 512 + p];
      float al = av[r];
      float sb = qv - al;
      sq += qv; sa += al; ss += sb;
      mq = fmaxf(mq, qv); ma = fmaxf(ma, al); ms = fmaxf(ms, sb);
      dacc[r] += qv * al;
    }
    // combine the two half-wave r-sets (lanes l and l^32 hold the same p)
    sq += __shfl_xor(sq, 32); sa += __shfl_xor(sa, 32); ss += __shfl_xor(ss, 32);
    mq = fmaxf(mq, __shfl_xor(mq, 32));
    ma = fmaxf(ma, __shfl_xor(ma, 32));
    ms = fmaxf(ms, __shfl_xor(ms, 32));
    if (lane < 32) {
      pb[p]        = (bf16)(sq * (1.f / 32.f));
      pb[512 + p]  = (bf16)(sa * (1.f / 32.f));
      pb[1024 + p] = (bf16)(ss * (1.f / 32.f));
      pb[1537 + p] = (bf16)mq;
      pb[2049 + p] = (bf16)ma;
      pb[2561 + p] = (bf16)ms;
    }
  }
  // dot[r] = sum_p q*align : butterfly over the 32-lane half, then LDS atomics
#pragma unroll
  for (int off = 1; off <= 16; off <<= 1) {
#pragma unroll
    for (int i = 0; i < 16; i++) dacc[i] += __shfl_xor(dacc[i], off);
  }
  if (ln == 0) {
#pragma unroll
    for (int i = 0; i < 16; i++) {
      int rp = (i & 3) + 8 * (i >> 2) + 4 * hl;
      atomicAdd(&dot_s[rp], dacc[i]);
    }
  }
  __syncthreads();
  if (tid < 32) {
    float d = dot_s[tid];
    float sm = d, mx = d;
#pragma unroll
    for (int off = 1; off <= 16; off <<= 1) {
      sm += __shfl_xor(sm, off);
      mx = fmaxf(mx, __shfl_xor(mx, off));
    }
    if (tid == 0) {
      pb[1536] = (bf16)(sm * (1.f / 32.f));
      pb[3073] = (bf16)mx;
    }
  }
  for (int z = tid; z < KPAD - 3074; z += 256) pb[3074 + z] = (bf16)0.f;
}

// ---------------------------------------------------------------------------
// ffn1: h = relu(pooled @ W1 + b1)   [4096 x 3136] @ [3136 x 512] -> bf16
// ---------------------------------------------------------------------------
__global__ __launch_bounds__(256, 2)
void ffn1_kernel(const bf16* __restrict__ pooled, const bf16* __restrict__ W1p,
                 const float* __restrict__ b1, bf16* __restrict__ hbuf)
{
  __shared__ bf16 At[2][128 * 64];
  const int bi = blockIdx.x;
  const int mstrip = bi >> 2, nstrip = bi & 3;
  const int row0 = mstrip * 128;
  const int tid = threadIdx.x;
  const int wid = tid >> 6, lane = tid & 63, hl = lane >> 5, ln = lane & 31;
  const int wr = wid >> 1, wc = wid & 1;

  const bf16* Wb0 = W1p + (size_t)(nstrip * 4 + wc * 2 + 0) * (KS1 * 512);
  const bf16* Wb1 = W1p + (size_t)(nstrip * 4 + wc * 2 + 1) * (KS1 * 512);

  f32x16 a00 = zero16(), a01 = zero16(), a10 = zero16(), a11 = zero16();

#pragma unroll
  for (int i = 0; i < 4; i++) {
    int s = tid + 256 * i;
    int r = s >> 3, c8 = s & 7;
    u32x4 tv = *(const u32x4*)(pooled + (size_t)(row0 + r) * KPAD + c8 * 8);
    *(u32x4*)((char*)At[0] + swz(r, c8 * 16)) = tv;
  }
  __syncthreads();

  u32x4 pf[4];
  for (int kc = 0; kc < 49; kc++) {
    const int cur = kc & 1;
    if (kc < 48) {
#pragma unroll
      for (int i = 0; i < 4; i++) {
        int s = tid + 256 * i;
        int r = s >> 3, c8 = s & 7;
        pf[i] = *(const u32x4*)(pooled + (size_t)(row0 + r) * KPAD + (kc + 1) * 64 + c8 * 8);
      }
    }
#pragma unroll
    for (int ks = 0; ks < 4; ks++) {
      const char* base = (const char*)At[cur];
      bf16x8 x0 = *(const bf16x8*)(base + swz(wr * 64 + ln,      ks * 32 + hl * 16));
      bf16x8 x1 = *(const bf16x8*)(base + swz(wr * 64 + 32 + ln, ks * 32 + hl * 16));
      size_t wo = ((size_t)(kc * 4 + ks) * 64 + lane) * 8;
      bf16x8 y0 = *(const bf16x8*)(Wb0 + wo);
      bf16x8 y1 = *(const bf16x8*)(Wb1 + wo);
      a00 = mfma16(x0, y0, a00); a01 = mfma16(x0, y1, a01);
      a10 = mfma16(x1, y0, a10); a11 = mfma16(x1, y1, a11);
    }
    if (kc < 48) {
#pragma unroll
      for (int i = 0; i < 4; i++) {
        int s = tid + 256 * i;
        int r = s >> 3, c8 = s & 7;
        *(u32x4*)((char*)At[cur ^ 1] + swz(r, c8 * 16)) = pf[i];
      }
    }
    __syncthreads();
  }

#pragma unroll
  for (int cc = 0; cc < 2; cc++) {
    const int n = nstrip * 128 + wc * 64 + cc * 32 + ln;
    const float bb = b1[n];
#pragma unroll
    for (int rc = 0; rc < 2; rc++) {
      f32x16 a = (cc == 0) ? (rc == 0 ? a00 : a10) : (rc == 0 ? a01 : a11);
      const int rowbase = row0 + wr * 64 + rc * 32;
#pragma unroll
      for (int r = 0; r < 16; r++) {
        int rp = (r & 3) + 8 * (r >> 2) + 4 * hl;
        hbuf[(size_t)(rowbase + rp) * 512 + n] = (bf16)fmaxf(a[r] + bb, 0.f);
      }
    }
  }
}

// ---------------------------------------------------------------------------
// ffn2: y = (h @ W2) * bnsc + bnsh   [4096 x 512] @ [512 x 32] -> fp32 out
// ---------------------------------------------------------------------------
__global__ __launch_bounds__(256, 2)
void ffn2_kernel(const bf16* __restrict__ hbuf, const bf16* __restrict__ W2p,
                 const float* __restrict__ bnsc, const float* __restrict__ bnsh,
                 float* __restrict__ out)
{
  __shared__ bf16 At[2][128 * 64];
  const int row0 = blockIdx.x * 128;
  const int tid = threadIdx.x;
  const int wid = tid >> 6, lane = tid & 63, hl = lane >> 5, ln = lane & 31;

  f32x16 a0 = zero16();

#pragma unroll
  for (int i = 0; i < 4; i++) {
    int s = tid + 256 * i;
    int r = s >> 3, c8 = s & 7;
    u32x4 tv = *(const u32x4*)(hbuf + (size_t)(row0 + r) * 512 + c8 * 8);
    *(u32x4*)((char*)At[0] + swz(r, c8 * 16)) = tv;
  }
  __syncthreads();

  u32x4 pf[4];
  for (int kc = 0; kc < 8; kc++) {
    const int cur = kc & 1;
    if (kc < 7) {
#pragma unroll
      for (int i = 0; i < 4; i++) {
        int s = tid + 256 * i;
        int r = s >> 3, c8 = s & 7;
        pf[i] = *(const u32x4*)(hbuf + (size_t)(row0 + r) * 512 + (kc + 1) * 64 + c8 * 8);
      }
    }
#pragma unroll
    for (int ks = 0; ks < 4; ks++) {
      const char* base = (const char*)At[cur];
      bf16x8 x0 = *(const bf16x8*)(base + swz(wid * 32 + ln, ks * 32 + hl * 16));
      bf16x8 y0 = *(const bf16x8*)(W2p + ((size_t)(kc * 4 + ks) * 64 + lane) * 8);
      a0 = mfma16(x0, y0, a0);
    }
    if (kc < 7) {
#pragma unroll
      for (int i = 0; i < 4; i++) {
        int s = tid + 256 * i;
        int r = s >> 3, c8 = s & 7;
        *(u32x4*)((char*)At[cur ^ 1] + swz(r, c8 * 16)) = pf[i];
      }
    }
    __syncthreads();
  }

  const float scl = bnsc[ln], sft = bnsh[ln];
#pragma unroll
  for (int r = 0; r < 16; r++) {
    int rp = (r & 3) + 8 * (r >> 2) + 4 * hl;
    out[(size_t)(row0 + wid * 32 + rp) * 32 + ln] = a0[r] * scl + sft;
  }
}

// ---------------------------------------------------------------------------
extern "C" void kernel_launch(void* const* d_in, const int* in_sizes, int n_in,
                              void* d_out, int out_size, void* d_ws, size_t ws_size,
                              hipStream_t stream)
{
  const float* content = (const float*)d_in[0];
  const float* image   = (const float*)d_in[1];
  const float* Wq = (const float*)d_in[2];
  const float* bq = (const float*)d_in[3];
  const float* Wk = (const float*)d_in[4];
  const float* bk = (const float*)d_in[5];
  const float* Wv = (const float*)d_in[6];
  const float* bv = (const float*)d_in[7];
  const float* W1 = (const float*)d_in[8];
  const float* b1 = (const float*)d_in[9];
  const float* W2 = (const float*)d_in[10];
  const float* b2 = (const float*)d_in[11];
  const float* gamma = (const float*)d_in[12];
  const float* beta  = (const float*)d_in[13];
  const float* mean  = (const float*)d_in[14];
  const float* var   = (const float*)d_in[15];
  float* out = (float*)d_out;

  char* ws = (char*)d_ws;
  size_t off = 0;
  auto alloc = [&](size_t bytes) { char* p = ws + off; off += bytes; return p; };
  bf16* qbuf   = (bf16*)alloc((size_t)131072 * 512 * 2);
  bf16* kbuf   = (bf16*)alloc((size_t)131072 * 512 * 2);
  bf16* vTbuf  = (bf16*)alloc((size_t)131072 * 512 * 2);
  bf16* pooled = (bf16*)alloc((size_t)4096 * KPAD * 2);
  bf16* hbuf   = (bf16*)alloc((size_t)4096 * 512 * 2);
  bf16* Wqp    = (bf16*)alloc((size_t)768 * 512 * 2);
  bf16* Wkp    = (bf16*)alloc((size_t)768 * 512 * 2);
  bf16* Wvp    = (bf16*)alloc((size_t)768 * 512 * 2);
  bf16* W1p    = (bf16*)alloc((size_t)KPAD * 512 * 2);
  bf16* W2p    = (bf16*)alloc((size_t)512 * 32 * 2);
  float* bnsc  = (float*)alloc(128);
  float* bnsh  = (float*)alloc(128);
  if (ws_size < off) return;  // signals cleanly via absmax if ws is too small

  prep_kernel<<<10944, 256, 0, stream>>>(Wq, Wk, Wv, W1, W2, b2, gamma, beta, mean, var,
                                         Wqp, Wkp, Wvp, W1p, W2p, bnsc, bnsh);
  proj_kernel<<<3072, 512, 0, stream>>>(content, image, Wqp, Wkp, Wvp, bq, bk, bv,
                                        qbuf, kbuf, vTbuf);
  attn_kernel<<<4096, 256, 0, stream>>>(qbuf, kbuf, vTbuf, pooled);
  ffn1_kernel<<<128, 256, 0, stream>>>(pooled, W1p, b1, hbuf);
  ffn2_kernel<<<32, 256, 0, stream>>>(hbuf, W2p, bnsc, bnsh, out);
}

// Round 15
// 846.420 us; speedup vs baseline: 7.8422x; 1.0383x over previous
//
#include <hip/hip_runtime.h>
#include <hip/hip_bf16.h>
#include <cstdint>

typedef __bf16 bf16;
typedef __attribute__((ext_vector_type(8)))  __bf16 bf16x8;
typedef __attribute__((ext_vector_type(4)))  __bf16 bf16x4;
typedef __attribute__((ext_vector_type(16))) float  f32x16;
typedef __attribute__((ext_vector_type(4)))  float  f32x4;
typedef __attribute__((ext_vector_type(4)))  unsigned int u32x4;

#define KPAD 3136   // FFN K (3074) padded to 49*64
#define KS1  196    // KPAD/16

__device__ __forceinline__ f32x16 zero16() {
  f32x16 z;
#pragma unroll
  for (int i = 0; i < 16; i++) z[i] = 0.f;
  return z;
}

__device__ __forceinline__ f32x16 mfma16(bf16x8 a, bf16x8 b, f32x16 c) {
  return __builtin_amdgcn_mfma_f32_32x32x16_bf16(a, b, c, 0, 0, 0);
}

// XOR swizzle for [rows][64] bf16 LDS tiles (row stride 128B) — used by ffn1/2.
__device__ __forceinline__ unsigned swz(unsigned row, unsigned bir) {
  return row * 128u + (bir ^ ((row & 7u) << 4));
}

// ---------------------------------------------------------------------------
// prep: pack weights into fragment-direct layout  packed[((ct*KS+ks)*64+lane)*8+j]
//       = W[ks*16 + 8*(lane>>5) + j][ct*32 + (lane&31)]   (zero-padded K for W1)
//       + fold BatchNorm (+b2) into per-col scale/shift.
// ---------------------------------------------------------------------------
__global__ void prep_kernel(const float* __restrict__ Wq, const float* __restrict__ Wk,
                            const float* __restrict__ Wv, const float* __restrict__ W1,
                            const float* __restrict__ W2, const float* __restrict__ b2,
                            const float* __restrict__ gamma, const float* __restrict__ beta,
                            const float* __restrict__ mean, const float* __restrict__ var,
                            bf16* __restrict__ Wqp, bf16* __restrict__ Wkp, bf16* __restrict__ Wvp,
                            bf16* __restrict__ W1p, bf16* __restrict__ W2p,
                            float* __restrict__ bnsc, float* __restrict__ bnsh)
{
  const size_t SQ = (size_t)16 * 48 * 512;
  const size_t S1 = (size_t)16 * KS1 * 512;
  const size_t S2 = (size_t)32 * 512;
  const size_t total = 3 * SQ + S1 + S2;
  size_t e = (size_t)blockIdx.x * 256 + threadIdx.x;
  if (e < total) {
    const float* src; bf16* dst; size_t idx; int KS, Ksrc, Ncol;
    if (e < SQ)              { src = Wq; dst = Wqp; idx = e;              KS = 48;  Ksrc = 768;  Ncol = 512; }
    else if (e < 2 * SQ)     { src = Wk; dst = Wkp; idx = e - SQ;         KS = 48;  Ksrc = 768;  Ncol = 512; }
    else if (e < 3 * SQ)     { src = Wv; dst = Wvp; idx = e - 2 * SQ;     KS = 48;  Ksrc = 768;  Ncol = 512; }
    else if (e < 3 * SQ + S1){ src = W1; dst = W1p; idx = e - 3 * SQ;     KS = KS1; Ksrc = 3074; Ncol = 512; }
    else                     { src = W2; dst = W2p; idx = e - 3 * SQ - S1;KS = 32;  Ksrc = 512;  Ncol = 32;  }
    size_t ctblk = (size_t)KS * 512;
    int ct = (int)(idx / ctblk);
    size_t rem = idx % ctblk;
    int ks = (int)(rem >> 9);
    int lrem = (int)(rem & 511);
    int lane = lrem >> 3, jj = lrem & 7;
    int k = ks * 16 + 8 * (lane >> 5) + jj;
    int n = ct * 32 + (lane & 31);
    float v = (k < Ksrc) ? src[(size_t)k * Ncol + n] : 0.f;
    dst[idx] = (bf16)v;
  }
  if (e < 32) {
    float rs = rsqrtf(var[e] + 1e-5f);
    float s = gamma[e] * rs;
    bnsc[e] = s;
    bnsh[e] = (b2[e] - mean[e]) * s + beta[e];
  }
}

// ---------------------------------------------------------------------------
// proj v15: wide-N (128 rows x 512 cols, 512 thr, 8 waves), LDS shrunk to
// 48KB (A dbuf 16KB + B SINGLE buffer 32KB) so 2 blocks/CU co-reside with
// margin (R14's 80KB x2 == exactly 160KB didn't fit -> occupancy never rose).
// Single-B requires the m97 2-barrier step, phased so vmcnt stays counted:
//   compute(t) -> PWRITE_A(t+1) -> lgkm+barrier1 -> STAGE_B(t+1) DMAs ->
//   ISSUE_A(t+2) -> vmcnt(2) [retires B's 4 in-order, keeps A(t+2)'s 2] ->
//   barrier2.
// The exposed B-DMA drain between barriers is covered by the SECOND resident
// block (the overlap every 1-block variant lacked).
// A: global fp32 -> depth-2 register stash -> cvt bf16 -> one ds_write_b128
// into fragment-direct layout (granule == tid; zero conflicts).
// Grid: 3 jobs (q,k,v) x 1024 mstrips; XCD-aware (bi&7 = XCD).
// v is written TRANSPOSED per batch: vT[b][p][m].
// ---------------------------------------------------------------------------

#define NSTEP 24  // K=768 / BK=32

#define AS1 __attribute__((address_space(1)))
#define AS3 __attribute__((address_space(3)))

// issue A k-chunk t into stash pfS: thread (ar32,aksl,ahl,aln) loads 8 fp32
// of row (row0+ar32*32+aln), cols t*32 + aksl*16 + ahl*8.
#define ISSUE_A(t, pfS) do {                                                   \
  const float* s_ = Asel + (size_t)(row0 + ar32 * 32 + aln) * 768              \
                    + (t) * 32 + aksl * 16 + ahl * 8;                          \
  pfS[0] = *(const f32x4*)s_;                                                  \
  pfS[1] = *(const f32x4*)(s_ + 4);                                            \
} while (0)

// cvt + single ds_write_b128; LDS granule == tid (frag-direct, conflict-free)
#define PWRITE_A(pfS, b2) do {                                                 \
  bf16x8 v_;                                                                   \
  _Pragma("unroll")                                                            \
  for (int q_ = 0; q_ < 4; q_++) { v_[q_] = (bf16)pfS[0][q_]; v_[4 + q_] = (bf16)pfS[1][q_]; } \
  *(bf16x8*)((char*)Ab[b2] + tid * 16) = v_;                                   \
} while (0)

// stage B k-chunk t (32 k x 512 cols, frag-direct) into the single Bb buffer
#define PSTAGE_B(t) do {                                                       \
  _Pragma("unroll")                                                            \
  for (int i_ = 0; i_ < 4; i_++) {                                             \
    int c_ = wid * 4 + i_;              /* 0..31 */                            \
    int ct_ = c_ >> 1, ksl_ = c_ & 1;                                          \
    const bf16* src_ = Wp + ((size_t)(ct_ * 48 + (t) * 2 + ksl_) * 64 + lane) * 8; \
    __builtin_amdgcn_global_load_lds(                                          \
      (const AS1 unsigned int*)src_,                                           \
      (AS3 unsigned int*)((char*)Bb + c_ * 1024), 16, 0, 0);                   \
  }                                                                            \
} while (0)

// A fragment: one conflict-free ds_read_b128
#define PFRAG(dst, b2, r32_, ksl_) do {                                        \
  dst = *(const bf16x8*)((const char*)Ab[b2] +                                 \
        (((((r32_) * 2 + (ksl_)) * 2 + hl) * 32) + ln) * 16);                  \
} while (0)

// compute tile t: 2 ksl x (2 A-frags + 4 B-frags x 2 accs) = 16 MFMA/wave
#define PCOMPUTE(b2a) do {                                                     \
  _Pragma("unroll")                                                            \
  for (int ksl_ = 0; ksl_ < 2; ksl_++) {                                       \
    bf16x8 x0_, x1_;                                                           \
    PFRAG(x0_, b2a, wr * 2 + 0, ksl_);                                         \
    PFRAG(x1_, b2a, wr * 2 + 1, ksl_);                                         \
    _Pragma("unroll")                                                          \
    for (int c4_ = 0; c4_ < 4; c4_++) {                                        \
      bf16x8 y_ = *(const bf16x8*)((const char*)Bb +                           \
                   (((wc4 * 4 + c4_) * 2 + ksl_) * 1024) + lane * 16);         \
      acc0[c4_] = mfma16(x0_, y_, acc0[c4_]);                                  \
      acc1[c4_] = mfma16(x1_, y_, acc1[c4_]);                                  \
    }                                                                          \
  }                                                                            \
} while (0)

// step t (2-barrier, single-B): compute(t) -> write A(t+1) -> barrier1 ->
// stage B(t+1) + issue A(t+2) -> vmcnt(2) -> barrier2.
#define PSTEP(t, pfWr, pfIs) do {                                              \
  PCOMPUTE((t) & 1);                                                           \
  if ((t) + 1 < NSTEP) {                                                       \
    PWRITE_A(pfWr, ((t) + 1) & 1);                                             \
    asm volatile("s_waitcnt lgkmcnt(0)" ::: "memory");                         \
    __builtin_amdgcn_s_barrier();                                              \
    __builtin_amdgcn_sched_barrier(0);                                         \
    PSTAGE_B((t) + 1);                                                         \
    if ((t) + 2 < NSTEP) { ISSUE_A((t) + 2, pfIs); }                           \
    __builtin_amdgcn_sched_barrier(0);                                         \
    if ((t) + 2 < NSTEP) { asm volatile("s_waitcnt vmcnt(2)" ::: "memory"); }  \
    else                 { asm volatile("s_waitcnt vmcnt(0)" ::: "memory"); }  \
    __builtin_amdgcn_s_barrier();                                              \
    __builtin_amdgcn_sched_barrier(0);                                         \
  }                                                                            \
} while (0)

__global__ __launch_bounds__(512, 2)
void proj_kernel(const float* __restrict__ content, const float* __restrict__ image,
                 const bf16* __restrict__ Wqp, const bf16* __restrict__ Wkp,
                 const bf16* __restrict__ Wvp,
                 const float* __restrict__ bq, const float* __restrict__ bk,
                 const float* __restrict__ bv,
                 bf16* __restrict__ qbuf, bf16* __restrict__ kbuf, bf16* __restrict__ vTbuf)
{
  __shared__ bf16 Ab[2][4096];     // 2 x 8KB bf16 A chunks (frag-direct)
  __shared__ bf16 Bb[16384];       // single 32KB frag-direct B chunk (48KB total)

  const int bi = blockIdx.x;
  const int xc = bi & 7;
  const int j  = bi >> 3;          // [0, 384)
  const int mstrip = xc * 128 + j / 3;
  const int t = j % 3;

  const float* Asel; const bf16* Wp; const float* bias; bf16* outp;
  int vmode;
  if (t == 0)      { Asel = content; Wp = Wqp; bias = bq; outp = qbuf;  vmode = 0; }
  else if (t == 1) { Asel = image;   Wp = Wkp; bias = bk; outp = kbuf;  vmode = 0; }
  else             { Asel = image;   Wp = Wvp; bias = bv; outp = vTbuf; vmode = 1; }

  const int row0 = mstrip * 128;
  const int tid = threadIdx.x;
  const int wid = tid >> 6, lane = tid & 63, hl = lane >> 5, ln = lane & 31;
  const int wr = wid >> 2, wc4 = wid & 3;   // row-half, col-quarter

  // A-staging role of this thread (granule == tid)
  const int ar32 = wid >> 1;       // row tile 0..3
  const int aksl = wid & 1;        // k slice 0..1
  const int ahl  = hl;             // k half-of-slice
  const int aln  = ln;             // row-in-tile

  // hoist bias loads (oldest VMEM; retired at the first implicit drain)
  float bsv[4];
#pragma unroll
  for (int c4 = 0; c4 < 4; c4++) bsv[c4] = bias[wc4 * 128 + c4 * 32 + ln];
  __builtin_amdgcn_sched_barrier(0);

  f32x16 acc0[4], acc1[4];
#pragma unroll
  for (int c4 = 0; c4 < 4; c4++) { acc0[c4] = zero16(); acc1[c4] = zero16(); }

  f32x4 pfA0[2], pfA1[2];   // depth-2 A stash: tile i in slot i&1

  // prologue: B(0) DMAs, A(0)->slot0, A(1)->slot1; PWRITE_A(slot0) waits
  // for A(0) (in-order this also retires bias + B(0)'s DMAs, A(1) stays in
  // flight); lgkm drain; barrier publishes Bb=B(0), Ab[0]=A(0).
  PSTAGE_B(0);
  ISSUE_A(0, pfA0);
  ISSUE_A(1, pfA1);
  __builtin_amdgcn_sched_barrier(0);
  PWRITE_A(pfA0, 0);
  asm volatile("s_waitcnt vmcnt(2)" ::: "memory");
  asm volatile("s_waitcnt lgkmcnt(0)" ::: "memory");
  __builtin_amdgcn_s_barrier();
  __builtin_amdgcn_sched_barrier(0);

  // tile i in stash slot i&1: pfWr = slot[(t+1)&1], pfIs = slot[t&1]
  PSTEP(0,  pfA1, pfA0);  PSTEP(1,  pfA0, pfA1);  PSTEP(2,  pfA1, pfA0);
  PSTEP(3,  pfA0, pfA1);  PSTEP(4,  pfA1, pfA0);  PSTEP(5,  pfA0, pfA1);
  PSTEP(6,  pfA1, pfA0);  PSTEP(7,  pfA0, pfA1);  PSTEP(8,  pfA1, pfA0);
  PSTEP(9,  pfA0, pfA1);  PSTEP(10, pfA1, pfA0);  PSTEP(11, pfA0, pfA1);
  PSTEP(12, pfA1, pfA0);  PSTEP(13, pfA0, pfA1);  PSTEP(14, pfA1, pfA0);
  PSTEP(15, pfA0, pfA1);  PSTEP(16, pfA1, pfA0);  PSTEP(17, pfA0, pfA1);
  PSTEP(18, pfA1, pfA0);  PSTEP(19, pfA0, pfA1);  PSTEP(20, pfA1, pfA0);
  PSTEP(21, pfA0, pfA1);  PSTEP(22, pfA1, pfA0);  PSTEP(23, pfA0, pfA1);

  // epilogue: C/D layout col=lane&31, row=(reg&3)+8*(reg>>2)+4*(lane>>5)
#pragma unroll
  for (int c4 = 0; c4 < 4; c4++) {
    const int n = wc4 * 128 + c4 * 32 + ln;
    const float bs = bsv[c4];
#pragma unroll
    for (int rt = 0; rt < 2; rt++) {
      f32x16 a = (rt == 0) ? acc0[c4] : acc1[c4];
      const int rowbase = row0 + wr * 64 + rt * 32;
      if (vmode == 0) {
#pragma unroll
        for (int r = 0; r < 16; r++) {
          int rp = (r & 3) + 8 * (r >> 2) + 4 * hl;
          outp[(size_t)(rowbase + rp) * 512 + n] = (bf16)(a[r] + bs);
        }
      } else {
        const int bidx = rowbase >> 5;   // 32-row groups == one batch
#pragma unroll
        for (int g = 0; g < 4; g++) {
          int m0 = g * 8 + 4 * hl;
          bf16x4 pk;
#pragma unroll
          for (int q2 = 0; q2 < 4; q2++) pk[q2] = (bf16)(a[g * 4 + q2] + bs);
          *(bf16x4*)(vTbuf + ((size_t)bidx * 512 + n) * 32 + m0) = pk;
        }
      }
    }
  }
}

// ---------------------------------------------------------------------------
// attn: one block per batch. scores (split-K MFMA) -> softmax -> align (MFMA on
// vT) -> features (q,align,sub,dot) -> mean/max pool -> pooled[b][3136] bf16.
// q/k/vT read straight from global (L2-hot, 96KB/batch); only ~24KB LDS.
// ---------------------------------------------------------------------------
__global__ __launch_bounds__(256, 4)
void attn_kernel(const bf16* __restrict__ qbuf, const bf16* __restrict__ kbuf,
                 const bf16* __restrict__ vTbuf, bf16* __restrict__ pooled)
{
  __shared__ float scp[4][32][33];
  __shared__ float sc[32][33];
  __shared__ bf16  attn_s[32][32];
  __shared__ float dot_s[32];

  const int b = blockIdx.x;
  const int tid = threadIdx.x;
  const int wid = tid >> 6, lane = tid & 63, hl = lane >> 5, ln = lane & 31;

  const bf16* qb = qbuf + (size_t)b * 32 * 512;
  const bf16* kb = kbuf + (size_t)b * 32 * 512;
  const bf16* vb = vTbuf + (size_t)b * 512 * 32;
  bf16* pb = pooled + (size_t)b * KPAD;

  if (tid < 32) dot_s[tid] = 0.f;

  // scores partials: wave w covers K-steps [w*8, w*8+8)
  f32x16 acc = zero16();
#pragma unroll
  for (int s8 = 0; s8 < 8; s8++) {
    int kk = wid * 8 + s8;
    int o = ln * 512 + kk * 16 + hl * 8;
    bf16x8 aq  = *(const bf16x8*)(qb + o);
    bf16x8 bk2 = *(const bf16x8*)(kb + o);
    acc = mfma16(aq, bk2, acc);
  }
#pragma unroll
  for (int r = 0; r < 16; r++) {
    int rp = (r & 3) + 8 * (r >> 2) + 4 * hl;
    scp[wid][rp][ln] = acc[r];
  }
  __syncthreads();
  for (int e = tid; e < 1024; e += 256) {
    int rr = e >> 5, mm = e & 31;
    sc[rr][mm] = (scp[0][rr][mm] + scp[1][rr][mm] + scp[2][rr][mm] + scp[3][rr][mm])
                 * 0.04419417382415922f;  // 1/sqrt(512)
  }
  __syncthreads();
  if (tid < 32) {
    float mx = -1e30f;
    for (int m = 0; m < 32; m++) mx = fmaxf(mx, sc[tid][m]);
    float sum = 0.f;
    for (int m = 0; m < 32; m++) { float ex = __expf(sc[tid][m] - mx); sum += ex; sc[tid][m] = ex; }
    float inv = 1.f / sum;
    for (int m = 0; m < 32; m++) attn_s[tid][m] = (bf16)(sc[tid][m] * inv);
  }
  __syncthreads();

  // align: A = attn (LDS), B = vT rows (global, contiguous 16B frags)
  bf16x8 pa0 = *(const bf16x8*)((const char*)attn_s + ln * 64 + hl * 16);
  bf16x8 pa1 = *(const bf16x8*)((const char*)attn_s + ln * 64 + 32 + hl * 16);

  float dacc[16];
#pragma unroll
  for (int i = 0; i < 16; i++) dacc[i] = 0.f;

  for (int cc = 0; cc < 4; cc++) {
    int ct = wid * 4 + cc;
    int p = ct * 32 + ln;
    f32x16 av = zero16();
    bf16x8 v0 = *(const bf16x8*)(vb + p * 32 + hl * 8);
    bf16x8 v1 = *(const bf16x8*)(vb + p * 32 + 16 + hl * 8);
    av = mfma16(pa0, v0, av);
    av = mfma16(pa1, v1, av);

    float sq = 0.f, sa = 0.f, ss = 0.f;
    float mq = -1e30f, ma = -1e30f, ms = -1e30f;
#pragma unroll
    for (int r = 0; r < 16; r++) {
      int rp = (r & 3) + 8 * (r >> 2) + 4 * hl;
      float qv = (float)qb[rp * 512 + p];
      float al = av[r];
      float sb = qv - al;
      sq += qv; sa += al; ss += sb;
      mq = fmaxf(mq, qv); ma = fmaxf(ma, al); ms = fmaxf(ms, sb);
      dacc[r] += qv * al;
    }
    // combine the two half-wave r-sets (lanes l and l^32 hold the same p)
    sq += __shfl_xor(sq, 32); sa += __shfl_xor(sa, 32); ss += __shfl_xor(ss, 32);
    mq = fmaxf(mq, __shfl_xor(mq, 32));
    ma = fmaxf(ma, __shfl_xor(ma, 32));
    ms = fmaxf(ms, __shfl_xor(ms, 32));
    if (lane < 32) {
      pb[p]        = (bf16)(sq * (1.f / 32.f));
      pb[512 + p]  = (bf16)(sa * (1.f / 32.f));
      pb[1024 + p] = (bf16)(ss * (1.f / 32.f));
      pb[1537 + p] = (bf16)mq;
      pb[2049 + p] = (bf16)ma;
      pb[2561 + p] = (bf16)ms;
    }
  }
  // dot[r] = sum_p q*align : butterfly over the 32-lane half, then LDS atomics
#pragma unroll
  for (int off = 1; off <= 16; off <<= 1) {
#pragma unroll
    for (int i = 0; i < 16; i++) dacc[i] += __shfl_xor(dacc[i], off);
  }
  if (ln == 0) {
#pragma unroll
    for (int i = 0; i < 16; i++) {
      int rp = (i & 3) + 8 * (i >> 2) + 4 * hl;
      atomicAdd(&dot_s[rp], dacc[i]);
    }
  }
  __syncthreads();
  if (tid < 32) {
    float d = dot_s[tid];
    float sm = d, mx = d;
#pragma unroll
    for (int off = 1; off <= 16; off <<= 1) {
      sm += __shfl_xor(sm, off);
      mx = fmaxf(mx, __shfl_xor(mx, off));
    }
    if (tid == 0) {
      pb[1536] = (bf16)(sm * (1.f / 32.f));
      pb[3073] = (bf16)mx;
    }
  }
  for (int z = tid; z < KPAD - 3074; z += 256) pb[3074 + z] = (bf16)0.f;
}

// ---------------------------------------------------------------------------
// ffn1: h = relu(pooled @ W1 + b1)   [4096 x 3136] @ [3136 x 512] -> bf16
// ---------------------------------------------------------------------------
__global__ __launch_bounds__(256, 2)
void ffn1_kernel(const bf16* __restrict__ pooled, const bf16* __restrict__ W1p,
                 const float* __restrict__ b1, bf16* __restrict__ hbuf)
{
  __shared__ bf16 At[2][128 * 64];
  const int bi = blockIdx.x;
  const int mstrip = bi >> 2, nstrip = bi & 3;
  const int row0 = mstrip * 128;
  const int tid = threadIdx.x;
  const int wid = tid >> 6, lane = tid & 63, hl = lane >> 5, ln = lane & 31;
  const int wr = wid >> 1, wc = wid & 1;

  const bf16* Wb0 = W1p + (size_t)(nstrip * 4 + wc * 2 + 0) * (KS1 * 512);
  const bf16* Wb1 = W1p + (size_t)(nstrip * 4 + wc * 2 + 1) * (KS1 * 512);

  f32x16 a00 = zero16(), a01 = zero16(), a10 = zero16(), a11 = zero16();

#pragma unroll
  for (int i = 0; i < 4; i++) {
    int s = tid + 256 * i;
    int r = s >> 3, c8 = s & 7;
    u32x4 tv = *(const u32x4*)(pooled + (size_t)(row0 + r) * KPAD + c8 * 8);
    *(u32x4*)((char*)At[0] + swz(r, c8 * 16)) = tv;
  }
  __syncthreads();

  u32x4 pf[4];
  for (int kc = 0; kc < 49; kc++) {
    const int cur = kc & 1;
    if (kc < 48) {
#pragma unroll
      for (int i = 0; i < 4; i++) {
        int s = tid + 256 * i;
        int r = s >> 3, c8 = s & 7;
        pf[i] = *(const u32x4*)(pooled + (size_t)(row0 + r) * KPAD + (kc + 1) * 64 + c8 * 8);
      }
    }
#pragma unroll
    for (int ks = 0; ks < 4; ks++) {
      const char* base = (const char*)At[cur];
      bf16x8 x0 = *(const bf16x8*)(base + swz(wr * 64 + ln,      ks * 32 + hl * 16));
      bf16x8 x1 = *(const bf16x8*)(base + swz(wr * 64 + 32 + ln, ks * 32 + hl * 16));
      size_t wo = ((size_t)(kc * 4 + ks) * 64 + lane) * 8;
      bf16x8 y0 = *(const bf16x8*)(Wb0 + wo);
      bf16x8 y1 = *(const bf16x8*)(Wb1 + wo);
      a00 = mfma16(x0, y0, a00); a01 = mfma16(x0, y1, a01);
      a10 = mfma16(x1, y0, a10); a11 = mfma16(x1, y1, a11);
    }
    if (kc < 48) {
#pragma unroll
      for (int i = 0; i < 4; i++) {
        int s = tid + 256 * i;
        int r = s >> 3, c8 = s & 7;
        *(u32x4*)((char*)At[cur ^ 1] + swz(r, c8 * 16)) = pf[i];
      }
    }
    __syncthreads();
  }

#pragma unroll
  for (int cc = 0; cc < 2; cc++) {
    const int n = nstrip * 128 + wc * 64 + cc * 32 + ln;
    const float bb = b1[n];
#pragma unroll
    for (int rc = 0; rc < 2; rc++) {
      f32x16 a = (cc == 0) ? (rc == 0 ? a00 : a10) : (rc == 0 ? a01 : a11);
      const int rowbase = row0 + wr * 64 + rc * 32;
#pragma unroll
      for (int r = 0; r < 16; r++) {
        int rp = (r & 3) + 8 * (r >> 2) + 4 * hl;
        hbuf[(size_t)(rowbase + rp) * 512 + n] = (bf16)fmaxf(a[r] + bb, 0.f);
      }
    }
  }
}

// ---------------------------------------------------------------------------
// ffn2: y = (h @ W2) * bnsc + bnsh   [4096 x 512] @ [512 x 32] -> fp32 out
// ---------------------------------------------------------------------------
__global__ __launch_bounds__(256, 2)
void ffn2_kernel(const bf16* __restrict__ hbuf, const bf16* __restrict__ W2p,
                 const float* __restrict__ bnsc, const float* __restrict__ bnsh,
                 float* __restrict__ out)
{
  __shared__ bf16 At[2][128 * 64];
  const int row0 = blockIdx.x * 128;
  const int tid = threadIdx.x;
  const int wid = tid >> 6, lane = tid & 63, hl = lane >> 5, ln = lane & 31;

  f32x16 a0 = zero16();

#pragma unroll
  for (int i = 0; i < 4; i++) {
    int s = tid + 256 * i;
    int r = s >> 3, c8 = s & 7;
    u32x4 tv = *(const u32x4*)(hbuf + (size_t)(row0 + r) * 512 + c8 * 8);
    *(u32x4*)((char*)At[0] + swz(r, c8 * 16)) = tv;
  }
  __syncthreads();

  u32x4 pf[4];
  for (int kc = 0; kc < 8; kc++) {
    const int cur = kc & 1;
    if (kc < 7) {
#pragma unroll
      for (int i = 0; i < 4; i++) {
        int s = tid + 256 * i;
        int r = s >> 3, c8 = s & 7;
        pf[i] = *(const u32x4*)(hbuf + (size_t)(row0 + r) * 512 + (kc + 1) * 64 + c8 * 8);
      }
    }
#pragma unroll
    for (int ks = 0; ks < 4; ks++) {
      const char* base = (const char*)At[cur];
      bf16x8 x0 = *(const bf16x8*)(base + swz(wid * 32 + ln, ks * 32 + hl * 16));
      bf16x8 y0 = *(const bf16x8*)(W2p + ((size_t)(kc * 4 + ks) * 64 + lane) * 8);
      a0 = mfma16(x0, y0, a0);
    }
    if (kc < 7) {
#pragma unroll
      for (int i = 0; i < 4; i++) {
        int s = tid + 256 * i;
        int r = s >> 3, c8 = s & 7;
        *(u32x4*)((char*)At[cur ^ 1] + swz(r, c8 * 16)) = pf[i];
      }
    }
    __syncthreads();
  }

  const float scl = bnsc[ln], sft = bnsh[ln];
#pragma unroll
  for (int r = 0; r < 16; r++) {
    int rp = (r & 3) + 8 * (r >> 2) + 4 * hl;
    out[(size_t)(row0 + wid * 32 + rp) * 32 + ln] = a0[r] * scl + sft;
  }
}

// ---------------------------------------------------------------------------
extern "C" void kernel_launch(void* const* d_in, const int* in_sizes, int n_in,
                              void* d_out, int out_size, void* d_ws, size_t ws_size,
                              hipStream_t stream)
{
  const float* content = (const float*)d_in[0];
  const float* image   = (const float*)d_in[1];
  const float* Wq = (const float*)d_in[2];
  const float* bq = (const float*)d_in[3];
  const float* Wk = (const float*)d_in[4];
  const float* bk = (const float*)d_in[5];
  const float* Wv = (const float*)d_in[6];
  const float* bv = (const float*)d_in[7];
  const float* W1 = (const float*)d_in[8];
  const float* b1 = (const float*)d_in[9];
  const float* W2 = (const float*)d_in[10];
  const float* b2 = (const float*)d_in[11];
  const float* gamma = (const float*)d_in[12];
  const float* beta  = (const float*)d_in[13];
  const float* mean  = (const float*)d_in[14];
  const float* var   = (const float*)d_in[15];
  float* out = (float*)d_out;

  char* ws = (char*)d_ws;
  size_t off = 0;
  auto alloc = [&](size_t bytes) { char* p = ws + off; off += bytes; return p; };
  bf16* qbuf   = (bf16*)alloc((size_t)131072 * 512 * 2);
  bf16* kbuf   = (bf16*)alloc((size_t)131072 * 512 * 2);
  bf16* vTbuf  = (bf16*)alloc((size_t)131072 * 512 * 2);
  bf16* pooled = (bf16*)alloc((size_t)4096 * KPAD * 2);
  bf16* hbuf   = (bf16*)alloc((size_t)4096 * 512 * 2);
  bf16* Wqp    = (bf16*)alloc((size_t)768 * 512 * 2);
  bf16* Wkp    = (bf16*)alloc((size_t)768 * 512 * 2);
  bf16* Wvp    = (bf16*)alloc((size_t)768 * 512 * 2);
  bf16* W1p    = (bf16*)alloc((size_t)KPAD * 512 * 2);
  bf16* W2p    = (bf16*)alloc((size_t)512 * 32 * 2);
  float* bnsc  = (float*)alloc(128);
  float* bnsh  = (float*)alloc(128);
  if (ws_size < off) return;  // signals cleanly via absmax if ws is too small

  prep_kernel<<<10944, 256, 0, stream>>>(Wq, Wk, Wv, W1, W2, b2, gamma, beta, mean, var,
                                         Wqp, Wkp, Wvp, W1p, W2p, bnsc, bnsh);
  proj_kernel<<<3072, 512, 0, stream>>>(content, image, Wqp, Wkp, Wvp, bq, bk, bv,
                                        qbuf, kbuf, vTbuf);
  attn_kernel<<<4096, 256, 0, stream>>>(qbuf, kbuf, vTbuf, pooled);
  ffn1_kernel<<<128, 256, 0, stream>>>(pooled, W1p, b1, hbuf);
  ffn2_kernel<<<32, 256, 0, stream>>>(hbuf, W2p, bnsc, bnsh, out);
}

// Round 16
// 818.018 us; speedup vs baseline: 8.1145x; 1.0347x over previous
//
#include <hip/hip_runtime.h>
#include <hip/hip_bf16.h>
#include <cstdint>

typedef __bf16 bf16;
typedef __attribute__((ext_vector_type(8)))  __bf16 bf16x8;
typedef __attribute__((ext_vector_type(4)))  __bf16 bf16x4;
typedef __attribute__((ext_vector_type(16))) float  f32x16;
typedef __attribute__((ext_vector_type(4)))  float  f32x4;
typedef __attribute__((ext_vector_type(4)))  unsigned int u32x4;

#define KPAD 3136   // FFN K (3074) padded to 49*64
#define KS1  196    // KPAD/16

__device__ __forceinline__ f32x16 zero16() {
  f32x16 z;
#pragma unroll
  for (int i = 0; i < 16; i++) z[i] = 0.f;
  return z;
}

__device__ __forceinline__ f32x16 mfma16(bf16x8 a, bf16x8 b, f32x16 c) {
  return __builtin_amdgcn_mfma_f32_32x32x16_bf16(a, b, c, 0, 0, 0);
}

// XOR swizzle for [rows][64] bf16 LDS tiles (row stride 128B) — used by ffn1/2.
__device__ __forceinline__ unsigned swz(unsigned row, unsigned bir) {
  return row * 128u + (bir ^ ((row & 7u) << 4));
}

// ---------------------------------------------------------------------------
// prep: pack weights into fragment-direct layout  packed[((ct*KS+ks)*64+lane)*8+j]
//       = W[ks*16 + 8*(lane>>5) + j][ct*32 + (lane&31)]   (zero-padded K for W1)
//       + fold BatchNorm (+b2) into per-col scale/shift.
// ---------------------------------------------------------------------------
__global__ void prep_kernel(const float* __restrict__ Wq, const float* __restrict__ Wk,
                            const float* __restrict__ Wv, const float* __restrict__ W1,
                            const float* __restrict__ W2, const float* __restrict__ b2,
                            const float* __restrict__ gamma, const float* __restrict__ beta,
                            const float* __restrict__ mean, const float* __restrict__ var,
                            bf16* __restrict__ Wqp, bf16* __restrict__ Wkp, bf16* __restrict__ Wvp,
                            bf16* __restrict__ W1p, bf16* __restrict__ W2p,
                            float* __restrict__ bnsc, float* __restrict__ bnsh)
{
  const size_t SQ = (size_t)16 * 48 * 512;
  const size_t S1 = (size_t)16 * KS1 * 512;
  const size_t S2 = (size_t)32 * 512;
  const size_t total = 3 * SQ + S1 + S2;
  size_t e = (size_t)blockIdx.x * 256 + threadIdx.x;
  if (e < total) {
    const float* src; bf16* dst; size_t idx; int KS, Ksrc, Ncol;
    if (e < SQ)              { src = Wq; dst = Wqp; idx = e;              KS = 48;  Ksrc = 768;  Ncol = 512; }
    else if (e < 2 * SQ)     { src = Wk; dst = Wkp; idx = e - SQ;         KS = 48;  Ksrc = 768;  Ncol = 512; }
    else if (e < 3 * SQ)     { src = Wv; dst = Wvp; idx = e - 2 * SQ;     KS = 48;  Ksrc = 768;  Ncol = 512; }
    else if (e < 3 * SQ + S1){ src = W1; dst = W1p; idx = e - 3 * SQ;     KS = KS1; Ksrc = 3074; Ncol = 512; }
    else                     { src = W2; dst = W2p; idx = e - 3 * SQ - S1;KS = 32;  Ksrc = 512;  Ncol = 32;  }
    size_t ctblk = (size_t)KS * 512;
    int ct = (int)(idx / ctblk);
    size_t rem = idx % ctblk;
    int ks = (int)(rem >> 9);
    int lrem = (int)(rem & 511);
    int lane = lrem >> 3, jj = lrem & 7;
    int k = ks * 16 + 8 * (lane >> 5) + jj;
    int n = ct * 32 + (lane & 31);
    float v = (k < Ksrc) ? src[(size_t)k * Ncol + n] : 0.f;
    dst[idx] = (bf16)v;
  }
  if (e < 32) {
    float rs = rsqrtf(var[e] + 1e-5f);
    float s = gamma[e] * rs;
    bnsc[e] = s;
    bnsh[e] = (b2[e] - mean[e]) * s + beta[e];
  }
}

// ---------------------------------------------------------------------------
// proj v16 = v10 (best-measured, 565us) + granule-transposed A layout:
// A stored in LDS as [g][row] (g = 16B granule within the 32-fp32 k-chunk,
// row = 0..127). DMA dest stays linear (L = c*64+lane); the SOURCE maps
// granule L to global (row=(c&1)*64+lane, g=c>>1). PFRAG reads granules
// (k0>>2)*128+row and +128: each 32-lane half reads 512 contiguous bytes ->
// CONFLICT-FREE, no XOR (v10 had 1.9e7 conflicts from the XOR'd row-major
// layout). Everything else (wide-N 128x512, 8 waves, triple-buffered 2-deep
// A+B DMA staging, vmcnt(6) counted drain, epilogues, grid) is R10-verbatim.
// Grid: 3 jobs (q,k,v) x 1024 mstrips; XCD-aware: bi&7 = XCD, 3 consecutive
// jobs share one A-panel (content / image / image) in L2.
// v is written TRANSPOSED per batch: vT[b][p][m].
// ---------------------------------------------------------------------------

#define NSTEP 24  // K=768 / BK=32

#define AS1 __attribute__((address_space(1)))
#define AS3 __attribute__((address_space(3)))

// stage A k-chunk t (128 rows x 32 fp32) into Ab[b3], granule-transposed:
// LDS granule L = c*64+lane holds global (row=(c&1)*64+lane, g=c>>1).
#define PSTAGE_A(t, b3) do {                                                   \
  const float* gb_ = Asel + (size_t)row0 * 768 + (t) * 32;                     \
  _Pragma("unroll")                                                            \
  for (int i_ = 0; i_ < 2; i_++) {                                             \
    int c_ = wid * 2 + i_;              /* chunk 0..15 (1KB each) */           \
    const float* src_ = gb_ + (size_t)((c_ & 1) * 64 + lane) * 768             \
                        + ((c_ >> 1) << 2);                                    \
    __builtin_amdgcn_global_load_lds(                                          \
      (const AS1 unsigned int*)src_,                                           \
      (AS3 unsigned int*)((char*)Ab[b3] + c_ * 1024), 16, 0, 0);               \
  }                                                                            \
} while (0)

// stage B k-chunk t (32 k x 512 cols, frag-direct) into Bb[b3]: 4 DMAs/thread
// chunk c = (ct<<1)|ksl holds packed frag (ct, ks = t*2+ksl), 1KB each.
#define PSTAGE_B(t, b3) do {                                                   \
  _Pragma("unroll")                                                            \
  for (int i_ = 0; i_ < 4; i_++) {                                             \
    int c_ = wid * 4 + i_;              /* 0..31 */                            \
    int ct_ = c_ >> 1, ksl_ = c_ & 1;                                          \
    const bf16* src_ = Wp + ((size_t)(ct_ * 48 + (t) * 2 + ksl_) * 64 + lane) * 8; \
    __builtin_amdgcn_global_load_lds(                                          \
      (const AS1 unsigned int*)src_,                                           \
      (AS3 unsigned int*)((char*)Bb[b3] + c_ * 1024), 16, 0, 0);               \
  }                                                                            \
} while (0)

// read one A-fragment (8 consecutive k fp32) from granule-transposed LDS,
// cvt to bf16. Granules (k0>>2)*128+row and +128 -> contiguous per half-wave,
// conflict-free.
#define PFRAG(dst, b3, row_, k0_) do {                                         \
  const char* lb_ = (const char*)Ab[b3];                                       \
  unsigned e_ = (unsigned)((k0_) >> 2);                                        \
  f32x4 lo_ = *(const f32x4*)(lb_ + ((e_)     * 128 + (row_)) * 16);           \
  f32x4 hi_ = *(const f32x4*)(lb_ + ((e_ + 1) * 128 + (row_)) * 16);           \
  _Pragma("unroll")                                                            \
  for (int j_ = 0; j_ < 4; j_++) { dst[j_] = (bf16)lo_[j_]; dst[4 + j_] = (bf16)hi_[j_]; } \
} while (0)

// compute tile t from buffers b3: 2 ksl x (2 A-frags + 4 B-frags + 8 MFMA)
#define PCOMPUTE(b3) do {                                                      \
  _Pragma("unroll")                                                            \
  for (int ksl_ = 0; ksl_ < 2; ksl_++) {                                       \
    bf16x8 x0_, x1_;                                                           \
    PFRAG(x0_, b3, wr * 64 + ln,      ksl_ * 16 + hl * 8);                     \
    PFRAG(x1_, b3, wr * 64 + 32 + ln, ksl_ * 16 + hl * 8);                     \
    _Pragma("unroll")                                                          \
    for (int c4_ = 0; c4_ < 4; c4_++) {                                        \
      bf16x8 y_ = *(const bf16x8*)((const char*)Bb[b3] +                       \
                   (((wc4 * 4 + c4_) * 2 + ksl_) * 1024) + lane * 16);         \
      acc0[c4_] = mfma16(x0_, y_, acc0[c4_]);                                  \
      acc1[c4_] = mfma16(x1_, y_, acc1[c4_]);                                  \
    }                                                                          \
  }                                                                            \
} while (0)

// step t: stage tile t+2 (6 DMAs), compute tile t, drain to vmcnt(6)
// (retires t+1's DMAs, keeps t+2's in flight), one barrier.
#define PSTEP(t) do {                                                          \
  if ((t) + 2 < NSTEP) {                                                       \
    PSTAGE_A((t) + 2, ((t) + 2) % 3);                                          \
    PSTAGE_B((t) + 2, ((t) + 2) % 3);                                          \
    __builtin_amdgcn_sched_barrier(0);                                         \
  }                                                                            \
  PCOMPUTE((t) % 3);                                                           \
  if ((t) + 1 < NSTEP) {                                                       \
    if ((t) + 2 < NSTEP) { asm volatile("s_waitcnt vmcnt(6)" ::: "memory"); }  \
    else                 { asm volatile("s_waitcnt vmcnt(0)" ::: "memory"); }  \
    __builtin_amdgcn_s_barrier();                                              \
    __builtin_amdgcn_sched_barrier(0);                                         \
  }                                                                            \
} while (0)

__global__ __launch_bounds__(512, 2)
void proj_kernel(const float* __restrict__ content, const float* __restrict__ image,
                 const bf16* __restrict__ Wqp, const bf16* __restrict__ Wkp,
                 const bf16* __restrict__ Wvp,
                 const float* __restrict__ bq, const float* __restrict__ bk,
                 const float* __restrict__ bv,
                 bf16* __restrict__ qbuf, bf16* __restrict__ kbuf, bf16* __restrict__ vTbuf)
{
  __shared__ float Ab[3][4096];    // 3 x 16KB fp32 A chunks (granule-transposed)
  __shared__ bf16  Bb[3][16384];   // 3 x 32KB frag-direct B chunks

  const int bi = blockIdx.x;
  const int xc = bi & 7;
  const int j  = bi >> 3;          // [0, 384)
  const int mstrip = xc * 128 + j / 3;
  const int t = j % 3;

  const float* Asel; const bf16* Wp; const float* bias; bf16* outp;
  int vmode;
  if (t == 0)      { Asel = content; Wp = Wqp; bias = bq; outp = qbuf;  vmode = 0; }
  else if (t == 1) { Asel = image;   Wp = Wkp; bias = bk; outp = kbuf;  vmode = 0; }
  else             { Asel = image;   Wp = Wvp; bias = bv; outp = vTbuf; vmode = 1; }

  const int row0 = mstrip * 128;
  const int tid = threadIdx.x;
  const int wid = tid >> 6, lane = tid & 63, hl = lane >> 5, ln = lane & 31;
  const int wr = wid >> 2, wc4 = wid & 3;   // row-half, col-quarter

  // hoist bias loads (oldest VMEM; retired at the prologue drain)
  float bsv[4];
#pragma unroll
  for (int c4 = 0; c4 < 4; c4++) bsv[c4] = bias[wc4 * 128 + c4 * 32 + ln];
  __builtin_amdgcn_sched_barrier(0);

  f32x16 acc0[4], acc1[4];
#pragma unroll
  for (int c4 = 0; c4 < 4; c4++) { acc0[c4] = zero16(); acc1[c4] = zero16(); }

  // prologue: stage tiles 0,1; drain to 6 (retires bias + tile0's 6 DMAs,
  // keeps tile1's 6 in flight); barrier publishes buf0.
  PSTAGE_A(0, 0); PSTAGE_B(0, 0);
  PSTAGE_A(1, 1); PSTAGE_B(1, 1);
  __builtin_amdgcn_sched_barrier(0);
  asm volatile("s_waitcnt vmcnt(6)" ::: "memory");
  __builtin_amdgcn_s_barrier();
  __builtin_amdgcn_sched_barrier(0);

  PSTEP(0);  PSTEP(1);  PSTEP(2);  PSTEP(3);  PSTEP(4);  PSTEP(5);
  PSTEP(6);  PSTEP(7);  PSTEP(8);  PSTEP(9);  PSTEP(10); PSTEP(11);
  PSTEP(12); PSTEP(13); PSTEP(14); PSTEP(15); PSTEP(16); PSTEP(17);
  PSTEP(18); PSTEP(19); PSTEP(20); PSTEP(21); PSTEP(22); PSTEP(23);

  // epilogue: C/D layout col=lane&31, row=(reg&3)+8*(reg>>2)+4*(lane>>5)
#pragma unroll
  for (int c4 = 0; c4 < 4; c4++) {
    const int n = wc4 * 128 + c4 * 32 + ln;
    const float bs = bsv[c4];
#pragma unroll
    for (int rt = 0; rt < 2; rt++) {
      f32x16 a = (rt == 0) ? acc0[c4] : acc1[c4];
      const int rowbase = row0 + wr * 64 + rt * 32;
      if (vmode == 0) {
#pragma unroll
        for (int r = 0; r < 16; r++) {
          int rp = (r & 3) + 8 * (r >> 2) + 4 * hl;
          outp[(size_t)(rowbase + rp) * 512 + n] = (bf16)(a[r] + bs);
        }
      } else {
        const int bidx = rowbase >> 5;   // 32-row groups == one batch
#pragma unroll
        for (int g = 0; g < 4; g++) {
          int m0 = g * 8 + 4 * hl;
          bf16x4 pk;
#pragma unroll
          for (int q2 = 0; q2 < 4; q2++) pk[q2] = (bf16)(a[g * 4 + q2] + bs);
          *(bf16x4*)(vTbuf + ((size_t)bidx * 512 + n) * 32 + m0) = pk;
        }
      }
    }
  }
}

// ---------------------------------------------------------------------------
// attn: one block per batch. scores (split-K MFMA) -> softmax -> align (MFMA on
// vT) -> features (q,align,sub,dot) -> mean/max pool -> pooled[b][3136] bf16.
// q/k/vT read straight from global (L2-hot, 96KB/batch); only ~24KB LDS.
// ---------------------------------------------------------------------------
__global__ __launch_bounds__(256, 4)
void attn_kernel(const bf16* __restrict__ qbuf, const bf16* __restrict__ kbuf,
                 const bf16* __restrict__ vTbuf, bf16* __restrict__ pooled)
{
  __shared__ float scp[4][32][33];
  __shared__ float sc[32][33];
  __shared__ bf16  attn_s[32][32];
  __shared__ float dot_s[32];

  const int b = blockIdx.x;
  const int tid = threadIdx.x;
  const int wid = tid >> 6, lane = tid & 63, hl = lane >> 5, ln = lane & 31;

  const bf16* qb = qbuf + (size_t)b * 32 * 512;
  const bf16* kb = kbuf + (size_t)b * 32 * 512;
  const bf16* vb = vTbuf + (size_t)b * 512 * 32;
  bf16* pb = pooled + (size_t)b * KPAD;

  if (tid < 32) dot_s[tid] = 0.f;

  // scores partials: wave w covers K-steps [w*8, w*8+8)
  f32x16 acc = zero16();
#pragma unroll
  for (int s8 = 0; s8 < 8; s8++) {
    int kk = wid * 8 + s8;
    int o = ln * 512 + kk * 16 + hl * 8;
    bf16x8 aq  = *(const bf16x8*)(qb + o);
    bf16x8 bk2 = *(const bf16x8*)(kb + o);
    acc = mfma16(aq, bk2, acc);
  }
#pragma unroll
  for (int r = 0; r < 16; r++) {
    int rp = (r & 3) + 8 * (r >> 2) + 4 * hl;
    scp[wid][rp][ln] = acc[r];
  }
  __syncthreads();
  for (int e = tid; e < 1024; e += 256) {
    int rr = e >> 5, mm = e & 31;
    sc[rr][mm] = (scp[0][rr][mm] + scp[1][rr][mm] + scp[2][rr][mm] + scp[3][rr][mm])
                 * 0.04419417382415922f;  // 1/sqrt(512)
  }
  __syncthreads();
  if (tid < 32) {
    float mx = -1e30f;
    for (int m = 0; m < 32; m++) mx = fmaxf(mx, sc[tid][m]);
    float sum = 0.f;
    for (int m = 0; m < 32; m++) { float ex = __expf(sc[tid][m] - mx); sum += ex; sc[tid][m] = ex; }
    float inv = 1.f / sum;
    for (int m = 0; m < 32; m++) attn_s[tid][m] = (bf16)(sc[tid][m] * inv);
  }
  __syncthreads();

  // align: A = attn (LDS), B = vT rows (global, contiguous 16B frags)
  bf16x8 pa0 = *(const bf16x8*)((const char*)attn_s + ln * 64 + hl * 16);
  bf16x8 pa1 = *(const bf16x8*)((const char*)attn_s + ln * 64 + 32 + hl * 16);

  float dacc[16];
#pragma unroll
  for (int i = 0; i < 16; i++) dacc[i] = 0.f;

  for (int cc = 0; cc < 4; cc++) {
    int ct = wid * 4 + cc;
    int p = ct * 32 + ln;
    f32x16 av = zero16();
    bf16x8 v0 = *(const bf16x8*)(vb + p * 32 + hl * 8);
    bf16x8 v1 = *(const bf16x8*)(vb + p * 32 + 16 + hl * 8);
    av = mfma16(pa0, v0, av);
    av = mfma16(pa1, v1, av);

    float sq = 0.f, sa = 0.f, ss = 0.f;
    float mq = -1e30f, ma = -1e30f, ms = -1e30f;
#pragma unroll
    for (int r = 0; r < 16; r++) {
      int rp = (r & 3) + 8 * (r >> 2) + 4 * hl;
      float qv = (float)qb[rp * 512 + p];
      float al = av[r];
      float sb = qv - al;
      sq += qv; sa += al; ss += sb;
      mq = fmaxf(mq, qv); ma = fmaxf(ma, al); ms = fmaxf(ms, sb);
      dacc[r] += qv * al;
    }
    // combine the two half-wave r-sets (lanes l and l^32 hold the same p)
    sq += __shfl_xor(sq, 32); sa += __shfl_xor(sa, 32); ss += __shfl_xor(ss, 32);
    mq = fmaxf(mq, __shfl_xor(mq, 32));
    ma = fmaxf(ma, __shfl_xor(ma, 32));
    ms = fmaxf(ms, __shfl_xor(ms, 32));
    if (lane < 32) {
      pb[p]        = (bf16)(sq * (1.f / 32.f));
      pb[512 + p]  = (bf16)(sa * (1.f / 32.f));
      pb[1024 + p] = (bf16)(ss * (1.f / 32.f));
      pb[1537 + p] = (bf16)mq;
      pb[2049 + p] = (bf16)ma;
      pb[2561 + p] = (bf16)ms;
    }
  }
  // dot[r] = sum_p q*align : butterfly over the 32-lane half, then LDS atomics
#pragma unroll
  for (int off = 1; off <= 16; off <<= 1) {
#pragma unroll
    for (int i = 0; i < 16; i++) dacc[i] += __shfl_xor(dacc[i], off);
  }
  if (ln == 0) {
#pragma unroll
    for (int i = 0; i < 16; i++) {
      int rp = (i & 3) + 8 * (i >> 2) + 4 * hl;
      atomicAdd(&dot_s[rp], dacc[i]);
    }
  }
  __syncthreads();
  if (tid < 32) {
    float d = dot_s[tid];
    float sm = d, mx = d;
#pragma unroll
    for (int off = 1; off <= 16; off <<= 1) {
      sm += __shfl_xor(sm, off);
      mx = fmaxf(mx, __shfl_xor(mx, off));
    }
    if (tid == 0) {
      pb[1536] = (bf16)(sm * (1.f / 32.f));
      pb[3073] = (bf16)mx;
    }
  }
  for (int z = tid; z < KPAD - 3074; z += 256) pb[3074 + z] = (bf16)0.f;
}

// ---------------------------------------------------------------------------
// ffn1: h = relu(pooled @ W1 + b1)   [4096 x 3136] @ [3136 x 512] -> bf16
// ---------------------------------------------------------------------------
__global__ __launch_bounds__(256, 2)
void ffn1_kernel(const bf16* __restrict__ pooled, const bf16* __restrict__ W1p,
                 const float* __restrict__ b1, bf16* __restrict__ hbuf)
{
  __shared__ bf16 At[2][128 * 64];
  const int bi = blockIdx.x;
  const int mstrip = bi >> 2, nstrip = bi & 3;
  const int row0 = mstrip * 128;
  const int tid = threadIdx.x;
  const int wid = tid >> 6, lane = tid & 63, hl = lane >> 5, ln = lane & 31;
  const int wr = wid >> 1, wc = wid & 1;

  const bf16* Wb0 = W1p + (size_t)(nstrip * 4 + wc * 2 + 0) * (KS1 * 512);
  const bf16* Wb1 = W1p + (size_t)(nstrip * 4 + wc * 2 + 1) * (KS1 * 512);

  f32x16 a00 = zero16(), a01 = zero16(), a10 = zero16(), a11 = zero16();

#pragma unroll
  for (int i = 0; i < 4; i++) {
    int s = tid + 256 * i;
    int r = s >> 3, c8 = s & 7;
    u32x4 tv = *(const u32x4*)(pooled + (size_t)(row0 + r) * KPAD + c8 * 8);
    *(u32x4*)((char*)At[0] + swz(r, c8 * 16)) = tv;
  }
  __syncthreads();

  u32x4 pf[4];
  for (int kc = 0; kc < 49; kc++) {
    const int cur = kc & 1;
    if (kc < 48) {
#pragma unroll
      for (int i = 0; i < 4; i++) {
        int s = tid + 256 * i;
        int r = s >> 3, c8 = s & 7;
        pf[i] = *(const u32x4*)(pooled + (size_t)(row0 + r) * KPAD + (kc + 1) * 64 + c8 * 8);
      }
    }
#pragma unroll
    for (int ks = 0; ks < 4; ks++) {
      const char* base = (const char*)At[cur];
      bf16x8 x0 = *(const bf16x8*)(base + swz(wr * 64 + ln,      ks * 32 + hl * 16));
      bf16x8 x1 = *(const bf16x8*)(base + swz(wr * 64 + 32 + ln, ks * 32 + hl * 16));
      size_t wo = ((size_t)(kc * 4 + ks) * 64 + lane) * 8;
      bf16x8 y0 = *(const bf16x8*)(Wb0 + wo);
      bf16x8 y1 = *(const bf16x8*)(Wb1 + wo);
      a00 = mfma16(x0, y0, a00); a01 = mfma16(x0, y1, a01);
      a10 = mfma16(x1, y0, a10); a11 = mfma16(x1, y1, a11);
    }
    if (kc < 48) {
#pragma unroll
      for (int i = 0; i < 4; i++) {
        int s = tid + 256 * i;
        int r = s >> 3, c8 = s & 7;
        *(u32x4*)((char*)At[cur ^ 1] + swz(r, c8 * 16)) = pf[i];
      }
    }
    __syncthreads();
  }

#pragma unroll
  for (int cc = 0; cc < 2; cc++) {
    const int n = nstrip * 128 + wc * 64 + cc * 32 + ln;
    const float bb = b1[n];
#pragma unroll
    for (int rc = 0; rc < 2; rc++) {
      f32x16 a = (cc == 0) ? (rc == 0 ? a00 : a10) : (rc == 0 ? a01 : a11);
      const int rowbase = row0 + wr * 64 + rc * 32;
#pragma unroll
      for (int r = 0; r < 16; r++) {
        int rp = (r & 3) + 8 * (r >> 2) + 4 * hl;
        hbuf[(size_t)(rowbase + rp) * 512 + n] = (bf16)fmaxf(a[r] + bb, 0.f);
      }
    }
  }
}

// ---------------------------------------------------------------------------
// ffn2: y = (h @ W2) * bnsc + bnsh   [4096 x 512] @ [512 x 32] -> fp32 out
// ---------------------------------------------------------------------------
__global__ __launch_bounds__(256, 2)
void ffn2_kernel(const bf16* __restrict__ hbuf, const bf16* __restrict__ W2p,
                 const float* __restrict__ bnsc, const float* __restrict__ bnsh,
                 float* __restrict__ out)
{
  __shared__ bf16 At[2][128 * 64];
  const int row0 = blockIdx.x * 128;
  const int tid = threadIdx.x;
  const int wid = tid >> 6, lane = tid & 63, hl = lane >> 5, ln = lane & 31;

  f32x16 a0 = zero16();

#pragma unroll
  for (int i = 0; i < 4; i++) {
    int s = tid + 256 * i;
    int r = s >> 3, c8 = s & 7;
    u32x4 tv = *(const u32x4*)(hbuf + (size_t)(row0 + r) * 512 + c8 * 8);
    *(u32x4*)((char*)At[0] + swz(r, c8 * 16)) = tv;
  }
  __syncthreads();

  u32x4 pf[4];
  for (int kc = 0; kc < 8; kc++) {
    const int cur = kc & 1;
    if (kc < 7) {
#pragma unroll
      for (int i = 0; i < 4; i++) {
        int s = tid + 256 * i;
        int r = s >> 3, c8 = s & 7;
        pf[i] = *(const u32x4*)(hbuf + (size_t)(row0 + r) * 512 + (kc + 1) * 64 + c8 * 8);
      }
    }
#pragma unroll
    for (int ks = 0; ks < 4; ks++) {
      const char* base = (const char*)At[cur];
      bf16x8 x0 = *(const bf16x8*)(base + swz(wid * 32 + ln, ks * 32 + hl * 16));
      bf16x8 y0 = *(const bf16x8*)(W2p + ((size_t)(kc * 4 + ks) * 64 + lane) * 8);
      a0 = mfma16(x0, y0, a0);
    }
    if (kc < 7) {
#pragma unroll
      for (int i = 0; i < 4; i++) {
        int s = tid + 256 * i;
        int r = s >> 3, c8 = s & 7;
        *(u32x4*)((char*)At[cur ^ 1] + swz(r, c8 * 16)) = pf[i];
      }
    }
    __syncthreads();
  }

  const float scl = bnsc[ln], sft = bnsh[ln];
#pragma unroll
  for (int r = 0; r < 16; r++) {
    int rp = (r & 3) + 8 * (r >> 2) + 4 * hl;
    out[(size_t)(row0 + wid * 32 + rp) * 32 + ln] = a0[r] * scl + sft;
  }
}

// ---------------------------------------------------------------------------
extern "C" void kernel_launch(void* const* d_in, const int* in_sizes, int n_in,
                              void* d_out, int out_size, void* d_ws, size_t ws_size,
                              hipStream_t stream)
{
  const float* content = (const float*)d_in[0];
  const float* image   = (const float*)d_in[1];
  const float* Wq = (const float*)d_in[2];
  const float* bq = (const float*)d_in[3];
  const float* Wk = (const float*)d_in[4];
  const float* bk = (const float*)d_in[5];
  const float* Wv = (const float*)d_in[6];
  const float* bv = (const float*)d_in[7];
  const float* W1 = (const float*)d_in[8];
  const float* b1 = (const float*)d_in[9];
  const float* W2 = (const float*)d_in[10];
  const float* b2 = (const float*)d_in[11];
  const float* gamma = (const float*)d_in[12];
  const float* beta  = (const float*)d_in[13];
  const float* mean  = (const float*)d_in[14];
  const float* var   = (const float*)d_in[15];
  float* out = (float*)d_out;

  char* ws = (char*)d_ws;
  size_t off = 0;
  auto alloc = [&](size_t bytes) { char* p = ws + off; off += bytes; return p; };
  bf16* qbuf   = (bf16*)alloc((size_t)131072 * 512 * 2);
  bf16* kbuf   = (bf16*)alloc((size_t)131072 * 512 * 2);
  bf16* vTbuf  = (bf16*)alloc((size_t)131072 * 512 * 2);
  bf16* pooled = (bf16*)alloc((size_t)4096 * KPAD * 2);
  bf16* hbuf   = (bf16*)alloc((size_t)4096 * 512 * 2);
  bf16* Wqp    = (bf16*)alloc((size_t)768 * 512 * 2);
  bf16* Wkp    = (bf16*)alloc((size_t)768 * 512 * 2);
  bf16* Wvp    = (bf16*)alloc((size_t)768 * 512 * 2);
  bf16* W1p    = (bf16*)alloc((size_t)KPAD * 512 * 2);
  bf16* W2p    = (bf16*)alloc((size_t)512 * 32 * 2);
  float* bnsc  = (float*)alloc(128);
  float* bnsh  = (float*)alloc(128);
  if (ws_size < off) return;  // signals cleanly via absmax if ws is too small

  prep_kernel<<<10944, 256, 0, stream>>>(Wq, Wk, Wv, W1, W2, b2, gamma, beta, mean, var,
                                         Wqp, Wkp, Wvp, W1p, W2p, bnsc, bnsh);
  proj_kernel<<<3072, 512, 0, stream>>>(content, image, Wqp, Wkp, Wvp, bq, bk, bv,
                                        qbuf, kbuf, vTbuf);
  attn_kernel<<<4096, 256, 0, stream>>>(qbuf, kbuf, vTbuf, pooled);
  ffn1_kernel<<<128, 256, 0, stream>>>(pooled, W1p, b1, hbuf);
  ffn2_kernel<<<32, 256, 0, stream>>>(hbuf, W2p, bnsc, bnsh, out);
}

// Round 17
// 752.060 us; speedup vs baseline: 8.8261x; 1.0877x over previous
//
#include <hip/hip_runtime.h>
#include <hip/hip_bf16.h>
#include <cstdint>

typedef __bf16 bf16;
typedef __attribute__((ext_vector_type(8)))  __bf16 bf16x8;
typedef __attribute__((ext_vector_type(4)))  __bf16 bf16x4;
typedef __attribute__((ext_vector_type(16))) float  f32x16;
typedef __attribute__((ext_vector_type(4)))  float  f32x4;
typedef __attribute__((ext_vector_type(4)))  unsigned int u32x4;

#define KPAD 3136   // FFN K (3074) padded to 49*64
#define KS1  196    // KPAD/16

__device__ __forceinline__ f32x16 zero16() {
  f32x16 z;
#pragma unroll
  for (int i = 0; i < 16; i++) z[i] = 0.f;
  return z;
}

__device__ __forceinline__ f32x16 mfma16(bf16x8 a, bf16x8 b, f32x16 c) {
  return __builtin_amdgcn_mfma_f32_32x32x16_bf16(a, b, c, 0, 0, 0);
}

// XOR swizzle for [rows][64] bf16 LDS tiles (row stride 128B) — used by ffn1/2.
__device__ __forceinline__ unsigned swz(unsigned row, unsigned bir) {
  return row * 128u + (bir ^ ((row & 7u) << 4));
}

// ---------------------------------------------------------------------------
// prep: pack weights into fragment-direct layout  packed[((ct*KS+ks)*64+lane)*8+j]
//       = W[ks*16 + 8*(lane>>5) + j][ct*32 + (lane&31)]   (zero-padded K for W1)
//       + fold BatchNorm (+b2) into per-col scale/shift.
// ---------------------------------------------------------------------------
__global__ void prep_kernel(const float* __restrict__ Wq, const float* __restrict__ Wk,
                            const float* __restrict__ Wv, const float* __restrict__ W1,
                            const float* __restrict__ W2, const float* __restrict__ b2,
                            const float* __restrict__ gamma, const float* __restrict__ beta,
                            const float* __restrict__ mean, const float* __restrict__ var,
                            bf16* __restrict__ Wqp, bf16* __restrict__ Wkp, bf16* __restrict__ Wvp,
                            bf16* __restrict__ W1p, bf16* __restrict__ W2p,
                            float* __restrict__ bnsc, float* __restrict__ bnsh)
{
  const size_t SQ = (size_t)16 * 48 * 512;
  const size_t S1 = (size_t)16 * KS1 * 512;
  const size_t S2 = (size_t)32 * 512;
  const size_t total = 3 * SQ + S1 + S2;
  size_t e = (size_t)blockIdx.x * 256 + threadIdx.x;
  if (e < total) {
    const float* src; bf16* dst; size_t idx; int KS, Ksrc, Ncol;
    if (e < SQ)              { src = Wq; dst = Wqp; idx = e;              KS = 48;  Ksrc = 768;  Ncol = 512; }
    else if (e < 2 * SQ)     { src = Wk; dst = Wkp; idx = e - SQ;         KS = 48;  Ksrc = 768;  Ncol = 512; }
    else if (e < 3 * SQ)     { src = Wv; dst = Wvp; idx = e - 2 * SQ;     KS = 48;  Ksrc = 768;  Ncol = 512; }
    else if (e < 3 * SQ + S1){ src = W1; dst = W1p; idx = e - 3 * SQ;     KS = KS1; Ksrc = 3074; Ncol = 512; }
    else                     { src = W2; dst = W2p; idx = e - 3 * SQ - S1;KS = 32;  Ksrc = 512;  Ncol = 32;  }
    size_t ctblk = (size_t)KS * 512;
    int ct = (int)(idx / ctblk);
    size_t rem = idx % ctblk;
    int ks = (int)(rem >> 9);
    int lrem = (int)(rem & 511);
    int lane = lrem >> 3, jj = lrem & 7;
    int k = ks * 16 + 8 * (lane >> 5) + jj;
    int n = ct * 32 + (lane & 31);
    float v = (k < Ksrc) ? src[(size_t)k * Ncol + n] : 0.f;
    dst[idx] = (bf16)v;
  }
  if (e < 32) {
    float rs = rsqrtf(var[e] + 1e-5f);
    float s = gamma[e] * rs;
    bnsc[e] = s;
    bnsh[e] = (b2[e] - mean[e]) * s + beta[e];
  }
}

// ---------------------------------------------------------------------------
// proj v10 (best-measured: proj 565us / total 752us): wide-N. Block = 128
// rows x 512 cols (ALL columns of one output), 512 threads = 8 waves
// (wr = wid>>2 row-half, wc4 = wid&3 col-quarter).
// A (128x32 fp32 = 16KB) and B (32x512 bf16 frag-direct = 32KB) both staged
// via global_load_lds, TRIPLE-buffered (144KB LDS): stage(t+2) issues while
// computing t; vmcnt(6) retires exactly tile(t+1)'s 6 DMAs/thread and keeps
// tile(t+2)'s in flight (counted, never 0 until the tail). A is staged ONCE
// per (mstrip,output) — amortized over all 512 cols.
// A: linear LDS dest + XOR-preswizzled source over 8 granules/row; reads
// apply the same XOR (4-way conflict max, coalesced DMA source — measured
// better than the conflict-free/non-coalesced variant, R16).
// fp32->bf16 cvt fused into the LDS->reg read.
// Grid: 3 jobs (q,k,v) x 1024 mstrips; XCD-aware: bi&7 = XCD, 3 consecutive
// jobs share one A-panel (content / image / image) in L2.
// v is written TRANSPOSED per batch: vT[b][p][m].
// ---------------------------------------------------------------------------

#define NSTEP 24  // K=768 / BK=32

#define AS1 __attribute__((address_space(1)))
#define AS3 __attribute__((address_space(3)))

// stage A k-chunk t (128 rows x 32 fp32) into Ab[b3]: 2 DMAs/thread
#define PSTAGE_A(t, b3) do {                                                   \
  const float* gb_ = Asel + (size_t)row0 * 768 + (t) * 32;                     \
  _Pragma("unroll")                                                            \
  for (int i_ = 0; i_ < 2; i_++) {                                             \
    int c_ = wid * 2 + i_;              /* chunk 0..15 (1KB each) */           \
    int G_ = c_ * 64 + lane;            /* granule 0..1023 */                  \
    int r_ = G_ >> 3, g_ = G_ & 7;                                             \
    const float* src_ = gb_ + (size_t)r_ * 768 + ((g_ ^ (r_ & 7)) << 2);       \
    __builtin_amdgcn_global_load_lds(                                          \
      (const AS1 unsigned int*)src_,                                           \
      (AS3 unsigned int*)((char*)Ab[b3] + c_ * 1024), 16, 0, 0);               \
  }                                                                            \
} while (0)

// stage B k-chunk t (32 k x 512 cols, frag-direct) into Bb[b3]: 4 DMAs/thread
// chunk c = (ct<<1)|ksl holds packed frag (ct, ks = t*2+ksl), 1KB each.
#define PSTAGE_B(t, b3) do {                                                   \
  _Pragma("unroll")                                                            \
  for (int i_ = 0; i_ < 4; i_++) {                                             \
    int c_ = wid * 4 + i_;              /* 0..31 */                            \
    int ct_ = c_ >> 1, ksl_ = c_ & 1;                                          \
    const bf16* src_ = Wp + ((size_t)(ct_ * 48 + (t) * 2 + ksl_) * 64 + lane) * 8; \
    __builtin_amdgcn_global_load_lds(                                          \
      (const AS1 unsigned int*)src_,                                           \
      (AS3 unsigned int*)((char*)Bb[b3] + c_ * 1024), 16, 0, 0);               \
  }                                                                            \
} while (0)

// read one A-fragment (8 consecutive k fp32) from swizzled LDS, cvt to bf16
#define PFRAG(dst, b3, row_, k0_) do {                                         \
  const char* lb_ = (const char*)Ab[b3];                                       \
  unsigned e_ = (unsigned)((k0_) >> 2);                                        \
  unsigned rx_ = (unsigned)((row_) & 7);                                       \
  f32x4 lo_ = *(const f32x4*)(lb_ + (row_) * 128 + (((e_)     ^ rx_) << 4));   \
  f32x4 hi_ = *(const f32x4*)(lb_ + (row_) * 128 + (((e_ + 1) ^ rx_) << 4));   \
  _Pragma("unroll")                                                            \
  for (int j_ = 0; j_ < 4; j_++) { dst[j_] = (bf16)lo_[j_]; dst[4 + j_] = (bf16)hi_[j_]; } \
} while (0)

// compute tile t from buffers b3: 2 ksl x (2 A-frags + 4 B-frags + 8 MFMA)
#define PCOMPUTE(b3) do {                                                      \
  _Pragma("unroll")                                                            \
  for (int ksl_ = 0; ksl_ < 2; ksl_++) {                                       \
    bf16x8 x0_, x1_;                                                           \
    PFRAG(x0_, b3, wr * 64 + ln,      ksl_ * 16 + hl * 8);                     \
    PFRAG(x1_, b3, wr * 64 + 32 + ln, ksl_ * 16 + hl * 8);                     \
    _Pragma("unroll")                                                          \
    for (int c4_ = 0; c4_ < 4; c4_++) {                                        \
      bf16x8 y_ = *(const bf16x8*)((const char*)Bb[b3] +                       \
                   (((wc4 * 4 + c4_) * 2 + ksl_) * 1024) + lane * 16);         \
      acc0[c4_] = mfma16(x0_, y_, acc0[c4_]);                                  \
      acc1[c4_] = mfma16(x1_, y_, acc1[c4_]);                                  \
    }                                                                          \
  }                                                                            \
} while (0)

// step t: stage tile t+2 (6 DMAs), compute tile t, drain to vmcnt(6)
// (retires t+1's DMAs, keeps t+2's in flight), one barrier.
#define PSTEP(t) do {                                                          \
  if ((t) + 2 < NSTEP) {                                                       \
    PSTAGE_A((t) + 2, ((t) + 2) % 3);                                          \
    PSTAGE_B((t) + 2, ((t) + 2) % 3);                                          \
    __builtin_amdgcn_sched_barrier(0);                                         \
  }                                                                            \
  PCOMPUTE((t) % 3);                                                           \
  if ((t) + 1 < NSTEP) {                                                       \
    if ((t) + 2 < NSTEP) { asm volatile("s_waitcnt vmcnt(6)" ::: "memory"); }  \
    else                 { asm volatile("s_waitcnt vmcnt(0)" ::: "memory"); }  \
    __builtin_amdgcn_s_barrier();                                              \
    __builtin_amdgcn_sched_barrier(0);                                         \
  }                                                                            \
} while (0)

__global__ __launch_bounds__(512, 2)
void proj_kernel(const float* __restrict__ content, const float* __restrict__ image,
                 const bf16* __restrict__ Wqp, const bf16* __restrict__ Wkp,
                 const bf16* __restrict__ Wvp,
                 const float* __restrict__ bq, const float* __restrict__ bk,
                 const float* __restrict__ bv,
                 bf16* __restrict__ qbuf, bf16* __restrict__ kbuf, bf16* __restrict__ vTbuf)
{
  __shared__ float Ab[3][4096];    // 3 x 16KB fp32 A chunks (src-swizzled)
  __shared__ bf16  Bb[3][16384];   // 3 x 32KB frag-direct B chunks

  const int bi = blockIdx.x;
  const int xc = bi & 7;
  const int j  = bi >> 3;          // [0, 384)
  const int mstrip = xc * 128 + j / 3;
  const int t = j % 3;

  const float* Asel; const bf16* Wp; const float* bias; bf16* outp;
  int vmode;
  if (t == 0)      { Asel = content; Wp = Wqp; bias = bq; outp = qbuf;  vmode = 0; }
  else if (t == 1) { Asel = image;   Wp = Wkp; bias = bk; outp = kbuf;  vmode = 0; }
  else             { Asel = image;   Wp = Wvp; bias = bv; outp = vTbuf; vmode = 1; }

  const int row0 = mstrip * 128;
  const int tid = threadIdx.x;
  const int wid = tid >> 6, lane = tid & 63, hl = lane >> 5, ln = lane & 31;
  const int wr = wid >> 2, wc4 = wid & 3;   // row-half, col-quarter

  // hoist bias loads (oldest VMEM; retired at the prologue drain)
  float bsv[4];
#pragma unroll
  for (int c4 = 0; c4 < 4; c4++) bsv[c4] = bias[wc4 * 128 + c4 * 32 + ln];
  __builtin_amdgcn_sched_barrier(0);

  f32x16 acc0[4], acc1[4];
#pragma unroll
  for (int c4 = 0; c4 < 4; c4++) { acc0[c4] = zero16(); acc1[c4] = zero16(); }

  // prologue: stage tiles 0,1; drain to 6 (retires bias + tile0's 6 DMAs,
  // keeps tile1's 6 in flight); barrier publishes buf0.
  PSTAGE_A(0, 0); PSTAGE_B(0, 0);
  PSTAGE_A(1, 1); PSTAGE_B(1, 1);
  __builtin_amdgcn_sched_barrier(0);
  asm volatile("s_waitcnt vmcnt(6)" ::: "memory");
  __builtin_amdgcn_s_barrier();
  __builtin_amdgcn_sched_barrier(0);

  PSTEP(0);  PSTEP(1);  PSTEP(2);  PSTEP(3);  PSTEP(4);  PSTEP(5);
  PSTEP(6);  PSTEP(7);  PSTEP(8);  PSTEP(9);  PSTEP(10); PSTEP(11);
  PSTEP(12); PSTEP(13); PSTEP(14); PSTEP(15); PSTEP(16); PSTEP(17);
  PSTEP(18); PSTEP(19); PSTEP(20); PSTEP(21); PSTEP(22); PSTEP(23);

  // epilogue: C/D layout col=lane&31, row=(reg&3)+8*(reg>>2)+4*(lane>>5)
#pragma unroll
  for (int c4 = 0; c4 < 4; c4++) {
    const int n = wc4 * 128 + c4 * 32 + ln;
    const float bs = bsv[c4];
#pragma unroll
    for (int rt = 0; rt < 2; rt++) {
      f32x16 a = (rt == 0) ? acc0[c4] : acc1[c4];
      const int rowbase = row0 + wr * 64 + rt * 32;
      if (vmode == 0) {
#pragma unroll
        for (int r = 0; r < 16; r++) {
          int rp = (r & 3) + 8 * (r >> 2) + 4 * hl;
          outp[(size_t)(rowbase + rp) * 512 + n] = (bf16)(a[r] + bs);
        }
      } else {
        const int bidx = rowbase >> 5;   // 32-row groups == one batch
#pragma unroll
        for (int g = 0; g < 4; g++) {
          int m0 = g * 8 + 4 * hl;
          bf16x4 pk;
#pragma unroll
          for (int q2 = 0; q2 < 4; q2++) pk[q2] = (bf16)(a[g * 4 + q2] + bs);
          *(bf16x4*)(vTbuf + ((size_t)bidx * 512 + n) * 32 + m0) = pk;
        }
      }
    }
  }
}

// ---------------------------------------------------------------------------
// attn: one block per batch. scores (split-K MFMA) -> softmax -> align (MFMA on
// vT) -> features (q,align,sub,dot) -> mean/max pool -> pooled[b][3136] bf16.
// q/k/vT read straight from global (L2-hot, 96KB/batch); only ~24KB LDS.
// ---------------------------------------------------------------------------
__global__ __launch_bounds__(256, 4)
void attn_kernel(const bf16* __restrict__ qbuf, const bf16* __restrict__ kbuf,
                 const bf16* __restrict__ vTbuf, bf16* __restrict__ pooled)
{
  __shared__ float scp[4][32][33];
  __shared__ float sc[32][33];
  __shared__ bf16  attn_s[32][32];
  __shared__ float dot_s[32];

  const int b = blockIdx.x;
  const int tid = threadIdx.x;
  const int wid = tid >> 6, lane = tid & 63, hl = lane >> 5, ln = lane & 31;

  const bf16* qb = qbuf + (size_t)b * 32 * 512;
  const bf16* kb = kbuf + (size_t)b * 32 * 512;
  const bf16* vb = vTbuf + (size_t)b * 512 * 32;
  bf16* pb = pooled + (size_t)b * KPAD;

  if (tid < 32) dot_s[tid] = 0.f;

  // scores partials: wave w covers K-steps [w*8, w*8+8)
  f32x16 acc = zero16();
#pragma unroll
  for (int s8 = 0; s8 < 8; s8++) {
    int kk = wid * 8 + s8;
    int o = ln * 512 + kk * 16 + hl * 8;
    bf16x8 aq  = *(const bf16x8*)(qb + o);
    bf16x8 bk2 = *(const bf16x8*)(kb + o);
    acc = mfma16(aq, bk2, acc);
  }
#pragma unroll
  for (int r = 0; r < 16; r++) {
    int rp = (r & 3) + 8 * (r >> 2) + 4 * hl;
    scp[wid][rp][ln] = acc[r];
  }
  __syncthreads();
  for (int e = tid; e < 1024; e += 256) {
    int rr = e >> 5, mm = e & 31;
    sc[rr][mm] = (scp[0][rr][mm] + scp[1][rr][mm] + scp[2][rr][mm] + scp[3][rr][mm])
                 * 0.04419417382415922f;  // 1/sqrt(512)
  }
  __syncthreads();
  if (tid < 32) {
    float mx = -1e30f;
    for (int m = 0; m < 32; m++) mx = fmaxf(mx, sc[tid][m]);
    float sum = 0.f;
    for (int m = 0; m < 32; m++) { float ex = __expf(sc[tid][m] - mx); sum += ex; sc[tid][m] = ex; }
    float inv = 1.f / sum;
    for (int m = 0; m < 32; m++) attn_s[tid][m] = (bf16)(sc[tid][m] * inv);
  }
  __syncthreads();

  // align: A = attn (LDS), B = vT rows (global, contiguous 16B frags)
  bf16x8 pa0 = *(const bf16x8*)((const char*)attn_s + ln * 64 + hl * 16);
  bf16x8 pa1 = *(const bf16x8*)((const char*)attn_s + ln * 64 + 32 + hl * 16);

  float dacc[16];
#pragma unroll
  for (int i = 0; i < 16; i++) dacc[i] = 0.f;

  for (int cc = 0; cc < 4; cc++) {
    int ct = wid * 4 + cc;
    int p = ct * 32 + ln;
    f32x16 av = zero16();
    bf16x8 v0 = *(const bf16x8*)(vb + p * 32 + hl * 8);
    bf16x8 v1 = *(const bf16x8*)(vb + p * 32 + 16 + hl * 8);
    av = mfma16(pa0, v0, av);
    av = mfma16(pa1, v1, av);

    float sq = 0.f, sa = 0.f, ss = 0.f;
    float mq = -1e30f, ma = -1e30f, ms = -1e30f;
#pragma unroll
    for (int r = 0; r < 16; r++) {
      int rp = (r & 3) + 8 * (r >> 2) + 4 * hl;
      float qv = (float)qb[rp * 512 + p];
      float al = av[r];
      float sb = qv - al;
      sq += qv; sa += al; ss += sb;
      mq = fmaxf(mq, qv); ma = fmaxf(ma, al); ms = fmaxf(ms, sb);
      dacc[r] += qv * al;
    }
    // combine the two half-wave r-sets (lanes l and l^32 hold the same p)
    sq += __shfl_xor(sq, 32); sa += __shfl_xor(sa, 32); ss += __shfl_xor(ss, 32);
    mq = fmaxf(mq, __shfl_xor(mq, 32));
    ma = fmaxf(ma, __shfl_xor(ma, 32));
    ms = fmaxf(ms, __shfl_xor(ms, 32));
    if (lane < 32) {
      pb[p]        = (bf16)(sq * (1.f / 32.f));
      pb[512 + p]  = (bf16)(sa * (1.f / 32.f));
      pb[1024 + p] = (bf16)(ss * (1.f / 32.f));
      pb[1537 + p] = (bf16)mq;
      pb[2049 + p] = (bf16)ma;
      pb[2561 + p] = (bf16)ms;
    }
  }
  // dot[r] = sum_p q*align : butterfly over the 32-lane half, then LDS atomics
#pragma unroll
  for (int off = 1; off <= 16; off <<= 1) {
#pragma unroll
    for (int i = 0; i < 16; i++) dacc[i] += __shfl_xor(dacc[i], off);
  }
  if (ln == 0) {
#pragma unroll
    for (int i = 0; i < 16; i++) {
      int rp = (i & 3) + 8 * (i >> 2) + 4 * hl;
      atomicAdd(&dot_s[rp], dacc[i]);
    }
  }
  __syncthreads();
  if (tid < 32) {
    float d = dot_s[tid];
    float sm = d, mx = d;
#pragma unroll
    for (int off = 1; off <= 16; off <<= 1) {
      sm += __shfl_xor(sm, off);
      mx = fmaxf(mx, __shfl_xor(mx, off));
    }
    if (tid == 0) {
      pb[1536] = (bf16)(sm * (1.f / 32.f));
      pb[3073] = (bf16)mx;
    }
  }
  for (int z = tid; z < KPAD - 3074; z += 256) pb[3074 + z] = (bf16)0.f;
}

// ---------------------------------------------------------------------------
// ffn1: h = relu(pooled @ W1 + b1)   [4096 x 3136] @ [3136 x 512] -> bf16
// ---------------------------------------------------------------------------
__global__ __launch_bounds__(256, 2)
void ffn1_kernel(const bf16* __restrict__ pooled, const bf16* __restrict__ W1p,
                 const float* __restrict__ b1, bf16* __restrict__ hbuf)
{
  __shared__ bf16 At[2][128 * 64];
  const int bi = blockIdx.x;
  const int mstrip = bi >> 2, nstrip = bi & 3;
  const int row0 = mstrip * 128;
  const int tid = threadIdx.x;
  const int wid = tid >> 6, lane = tid & 63, hl = lane >> 5, ln = lane & 31;
  const int wr = wid >> 1, wc = wid & 1;

  const bf16* Wb0 = W1p + (size_t)(nstrip * 4 + wc * 2 + 0) * (KS1 * 512);
  const bf16* Wb1 = W1p + (size_t)(nstrip * 4 + wc * 2 + 1) * (KS1 * 512);

  f32x16 a00 = zero16(), a01 = zero16(), a10 = zero16(), a11 = zero16();

#pragma unroll
  for (int i = 0; i < 4; i++) {
    int s = tid + 256 * i;
    int r = s >> 3, c8 = s & 7;
    u32x4 tv = *(const u32x4*)(pooled + (size_t)(row0 + r) * KPAD + c8 * 8);
    *(u32x4*)((char*)At[0] + swz(r, c8 * 16)) = tv;
  }
  __syncthreads();

  u32x4 pf[4];
  for (int kc = 0; kc < 49; kc++) {
    const int cur = kc & 1;
    if (kc < 48) {
#pragma unroll
      for (int i = 0; i < 4; i++) {
        int s = tid + 256 * i;
        int r = s >> 3, c8 = s & 7;
        pf[i] = *(const u32x4*)(pooled + (size_t)(row0 + r) * KPAD + (kc + 1) * 64 + c8 * 8);
      }
    }
#pragma unroll
    for (int ks = 0; ks < 4; ks++) {
      const char* base = (const char*)At[cur];
      bf16x8 x0 = *(const bf16x8*)(base + swz(wr * 64 + ln,      ks * 32 + hl * 16));
      bf16x8 x1 = *(const bf16x8*)(base + swz(wr * 64 + 32 + ln, ks * 32 + hl * 16));
      size_t wo = ((size_t)(kc * 4 + ks) * 64 + lane) * 8;
      bf16x8 y0 = *(const bf16x8*)(Wb0 + wo);
      bf16x8 y1 = *(const bf16x8*)(Wb1 + wo);
      a00 = mfma16(x0, y0, a00); a01 = mfma16(x0, y1, a01);
      a10 = mfma16(x1, y0, a10); a11 = mfma16(x1, y1, a11);
    }
    if (kc < 48) {
#pragma unroll
      for (int i = 0; i < 4; i++) {
        int s = tid + 256 * i;
        int r = s >> 3, c8 = s & 7;
        *(u32x4*)((char*)At[cur ^ 1] + swz(r, c8 * 16)) = pf[i];
      }
    }
    __syncthreads();
  }

#pragma unroll
  for (int cc = 0; cc < 2; cc++) {
    const int n = nstrip * 128 + wc * 64 + cc * 32 + ln;
    const float bb = b1[n];
#pragma unroll
    for (int rc = 0; rc < 2; rc++) {
      f32x16 a = (cc == 0) ? (rc == 0 ? a00 : a10) : (rc == 0 ? a01 : a11);
      const int rowbase = row0 + wr * 64 + rc * 32;
#pragma unroll
      for (int r = 0; r < 16; r++) {
        int rp = (r & 3) + 8 * (r >> 2) + 4 * hl;
        hbuf[(size_t)(rowbase + rp) * 512 + n] = (bf16)fmaxf(a[r] + bb, 0.f);
      }
    }
  }
}

// ---------------------------------------------------------------------------
// ffn2: y = (h @ W2) * bnsc + bnsh   [4096 x 512] @ [512 x 32] -> fp32 out
// ---------------------------------------------------------------------------
__global__ __launch_bounds__(256, 2)
void ffn2_kernel(const bf16* __restrict__ hbuf, const bf16* __restrict__ W2p,
                 const float* __restrict__ bnsc, const float* __restrict__ bnsh,
                 float* __restrict__ out)
{
  __shared__ bf16 At[2][128 * 64];
  const int row0 = blockIdx.x * 128;
  const int tid = threadIdx.x;
  const int wid = tid >> 6, lane = tid & 63, hl = lane >> 5, ln = lane & 31;

  f32x16 a0 = zero16();

#pragma unroll
  for (int i = 0; i < 4; i++) {
    int s = tid + 256 * i;
    int r = s >> 3, c8 = s & 7;
    u32x4 tv = *(const u32x4*)(hbuf + (size_t)(row0 + r) * 512 + c8 * 8);
    *(u32x4*)((char*)At[0] + swz(r, c8 * 16)) = tv;
  }
  __syncthreads();

  u32x4 pf[4];
  for (int kc = 0; kc < 8; kc++) {
    const int cur = kc & 1;
    if (kc < 7) {
#pragma unroll
      for (int i = 0; i < 4; i++) {
        int s = tid + 256 * i;
        int r = s >> 3, c8 = s & 7;
        pf[i] = *(const u32x4*)(hbuf + (size_t)(row0 + r) * 512 + (kc + 1) * 64 + c8 * 8);
      }
    }
#pragma unroll
    for (int ks = 0; ks < 4; ks++) {
      const char* base = (const char*)At[cur];
      bf16x8 x0 = *(const bf16x8*)(base + swz(wid * 32 + ln, ks * 32 + hl * 16));
      bf16x8 y0 = *(const bf16x8*)(W2p + ((size_t)(kc * 4 + ks) * 64 + lane) * 8);
      a0 = mfma16(x0, y0, a0);
    }
    if (kc < 7) {
#pragma unroll
      for (int i = 0; i < 4; i++) {
        int s = tid + 256 * i;
        int r = s >> 3, c8 = s & 7;
        *(u32x4*)((char*)At[cur ^ 1] + swz(r, c8 * 16)) = pf[i];
      }
    }
    __syncthreads();
  }

  const float scl = bnsc[ln], sft = bnsh[ln];
#pragma unroll
  for (int r = 0; r < 16; r++) {
    int rp = (r & 3) + 8 * (r >> 2) + 4 * hl;
    out[(size_t)(row0 + wid * 32 + rp) * 32 + ln] = a0[r] * scl + sft;
  }
}

// ---------------------------------------------------------------------------
extern "C" void kernel_launch(void* const* d_in, const int* in_sizes, int n_in,
                              void* d_out, int out_size, void* d_ws, size_t ws_size,
                              hipStream_t stream)
{
  const float* content = (const float*)d_in[0];
  const float* image   = (const float*)d_in[1];
  const float* Wq = (const float*)d_in[2];
  const float* bq = (const float*)d_in[3];
  const float* Wk = (const float*)d_in[4];
  const float* bk = (const float*)d_in[5];
  const float* Wv = (const float*)d_in[6];
  const float* bv = (const float*)d_in[7];
  const float* W1 = (const float*)d_in[8];
  const float* b1 = (const float*)d_in[9];
  const float* W2 = (const float*)d_in[10];
  const float* b2 = (const float*)d_in[11];
  const float* gamma = (const float*)d_in[12];
  const float* beta  = (const float*)d_in[13];
  const float* mean  = (const float*)d_in[14];
  const float* var   = (const float*)d_in[15];
  float* out = (float*)d_out;

  char* ws = (char*)d_ws;
  size_t off = 0;
  auto alloc = [&](size_t bytes) { char* p = ws + off; off += bytes; return p; };
  bf16* qbuf   = (bf16*)alloc((size_t)131072 * 512 * 2);
  bf16* kbuf   = (bf16*)alloc((size_t)131072 * 512 * 2);
  bf16* vTbuf  = (bf16*)alloc((size_t)131072 * 512 * 2);
  bf16* pooled = (bf16*)alloc((size_t)4096 * KPAD * 2);
  bf16* hbuf   = (bf16*)alloc((size_t)4096 * 512 * 2);
  bf16* Wqp    = (bf16*)alloc((size_t)768 * 512 * 2);
  bf16* Wkp    = (bf16*)alloc((size_t)768 * 512 * 2);
  bf16* Wvp    = (bf16*)alloc((size_t)768 * 512 * 2);
  bf16* W1p    = (bf16*)alloc((size_t)KPAD * 512 * 2);
  bf16* W2p    = (bf16*)alloc((size_t)512 * 32 * 2);
  float* bnsc  = (float*)alloc(128);
  float* bnsh  = (float*)alloc(128);
  if (ws_size < off) return;  // signals cleanly via absmax if ws is too small

  prep_kernel<<<10944, 256, 0, stream>>>(Wq, Wk, Wv, W1, W2, b2, gamma, beta, mean, var,
                                         Wqp, Wkp, Wvp, W1p, W2p, bnsc, bnsh);
  proj_kernel<<<3072, 512, 0, stream>>>(content, image, Wqp, Wkp, Wvp, bq, bk, bv,
                                        qbuf, kbuf, vTbuf);
  attn_kernel<<<4096, 256, 0, stream>>>(qbuf, kbuf, vTbuf, pooled);
  ffn1_kernel<<<128, 256, 0, stream>>>(pooled, W1p, b1, hbuf);
  ffn2_kernel<<<32, 256, 0, stream>>>(hbuf, W2p, bnsc, bnsh, out);
}